// Round 9
// baseline (1250.563 us; speedup 1.0000x reference)
//
#include <hip/hip_runtime.h>
#include <hip/hip_fp16.h>

#define BN_EPS 1e-5f
#define CAP 8192        // max edges per bucket (mean ~4092; 2x headroom)
#define MAXBKT 512      // supports N up to 131072 (src must fit 24 bits)

typedef _Float16 half8 __attribute__((ext_vector_type(8)));
typedef float f32x4 __attribute__((ext_vector_type(4)));

__device__ __forceinline__ int get_xcc() {
    unsigned x;
    asm volatile("s_getreg_b32 %0, hwreg(HW_REG_XCC_ID)" : "=s"(x));
    return (int)(x & 7);
}

// ---------------- bucketed CSR build (packed: src | dstlo<<24) ----------------

__global__ void k_init(int* bucket_cur, int* wcnt, int* rowptr, int n, int E) {
    int i = blockIdx.x * blockDim.x + threadIdx.x;
    if (i < MAXBKT) bucket_cur[i] = 0;
    if (i < 32) wcnt[i] = 0;
    if (i == 0) rowptr[n] = E;
}

__global__ __launch_bounds__(256) void k_bin(const int* __restrict__ src,
        const int* __restrict__ dst, int E, int nbk,
        int* __restrict__ bucket_cur, unsigned* __restrict__ pairs) {
    __shared__ int hist[MAXBKT];
    __shared__ int base_[MAXBKT];
    for (int b = threadIdx.x; b < nbk; b += 256) hist[b] = 0;
    __syncthreads();
    int e0 = blockIdx.x * 2048;
    int my_b[8], my_l[8];
    unsigned my_p[8];
    #pragma unroll
    for (int j = 0; j < 8; j++) {
        int e = e0 + threadIdx.x + j * 256;
        my_b[j] = -1;
        if (e < E) {
            int d = dst[e];
            my_p[j] = (unsigned)src[e] | ((unsigned)(d & 255) << 24);
            my_b[j] = d >> 8;
            my_l[j] = atomicAdd(&hist[my_b[j]], 1);
        }
    }
    __syncthreads();
    for (int b = threadIdx.x; b < nbk; b += 256) {
        int h = hist[b];
        base_[b] = h ? atomicAdd(&bucket_cur[b], h) : 0;
    }
    __syncthreads();
    #pragma unroll
    for (int j = 0; j < 8; j++) {
        if (my_b[j] >= 0) {
            int pos = base_[my_b[j]] + my_l[j];
            if (pos < CAP)
                pairs[(size_t)my_b[j] * CAP + pos] = my_p[j];
        }
    }
}

// per-bucket: degree hist + block-exclusive-scan + dinv (one pass over pairs)
__global__ __launch_bounds__(256) void k_cntscan(const unsigned* __restrict__ pairs,
        const int* __restrict__ bucket_cur, int* __restrict__ rowptr,
        int* __restrict__ bsums, float* __restrict__ dinv, int n) {
    __shared__ int lc[256];
    __shared__ int tmp[256];
    lc[threadIdx.x] = 0;
    __syncthreads();
    int b = blockIdx.x;
    int m = min(bucket_cur[b], CAP);
    const unsigned* p = pairs + (size_t)b * CAP;
    for (int q = threadIdx.x; q < m; q += 256)
        atomicAdd(&lc[p[q] >> 24], 1);
    __syncthreads();
    int v = lc[threadIdx.x];
    tmp[threadIdx.x] = v;
    __syncthreads();
    for (int off = 1; off < 256; off <<= 1) {
        int t = (threadIdx.x >= off) ? tmp[threadIdx.x - off] : 0;
        __syncthreads();
        tmp[threadIdx.x] += t;
        __syncthreads();
    }
    int node = b * 256 + threadIdx.x;
    if (node < n) {
        rowptr[node] = tmp[threadIdx.x] - v;   // bucket-local exclusive
        dinv[node] = rsqrtf((float)v + 1.0f);
    }
    if (threadIdx.x == 255) bsums[b] = tmp[255];
}

__global__ void k_scan2(int* bsums, int nb) {
    __shared__ int tmp[1024];
    int v = (threadIdx.x < nb) ? bsums[threadIdx.x] : 0;
    tmp[threadIdx.x] = v;
    __syncthreads();
    for (int off = 1; off < 1024; off <<= 1) {
        int t = (threadIdx.x >= off) ? tmp[threadIdx.x - off] : 0;
        __syncthreads();
        tmp[threadIdx.x] += t;
        __syncthreads();
    }
    if (threadIdx.x < nb) bsums[threadIdx.x] = tmp[threadIdx.x] - v;  // exclusive
}

__global__ void k_scan3(int* __restrict__ rowptr, const int* __restrict__ bsums, int n) {
    int i = blockIdx.x * blockDim.x + threadIdx.x;
    if (i < n) rowptr[i] += bsums[i >> 8];
}

__global__ __launch_bounds__(256) void k_fill2(const unsigned* __restrict__ pairs,
        const int* __restrict__ bucket_cur, const int* __restrict__ rowptr,
        int* __restrict__ csr, int n) {
    __shared__ int cur[256];
    __shared__ int stg[CAP];
    int b = blockIdx.x;
    int node0 = b * 256;
    int nend = min(node0 + 256, n);
    int base_csr = rowptr[node0];
    int node = node0 + threadIdx.x;
    cur[threadIdx.x] = (node < n) ? rowptr[node] - base_csr : 0;
    __syncthreads();
    int m = min(bucket_cur[b], CAP);
    const unsigned* p = pairs + (size_t)b * CAP;
    for (int q = threadIdx.x; q < m; q += 256) {
        unsigned pr = p[q];
        int ofs = atomicAdd(&cur[pr >> 24], 1);
        stg[ofs] = (int)(pr & 0xFFFFFFu);
    }
    __syncthreads();
    int len = rowptr[nend] - base_csr;
    for (int q = threadIdx.x; q < len; q += 256)
        csr[base_csr + q] = stg[q];
}

// ---------------- W pack: fp32 [128][M] -> fp16 hi/lo lane fragments ----------------

template<int M>
__global__ void k_wpack(const float* __restrict__ W, half8* __restrict__ Wp) {
    int idx = blockIdx.x * 256 + threadIdx.x;
    constexpr int TOT = (M / 16) * 4 * 64;
    if (idx >= TOT) return;
    int l = idx & 63, tc = idx >> 6;
    int c = tc & 3, t = tc >> 2;
    int g = l >> 4, nn = l & 15;
    int k0 = 32 * c + 8 * g, col = 16 * t + nn;
    half8 hi, lo;
    #pragma unroll
    for (int j = 0; j < 8; j++) {
        float w = W[(size_t)(k0 + j) * M + col];
        _Float16 h = (_Float16)w;
        hi[j] = h;
        lo[j] = (_Float16)(w - (float)h);
    }
    Wp[idx] = hi;
    Wp[TOT + idx] = lo;
}

// ---------------- helpers ----------------

__device__ __forceinline__ void h8_acc(float* acc, uint4 v) {
    const __half2* p = (const __half2*)&v;
    #pragma unroll
    for (int j = 0; j < 4; j++) {
        float2 f = __half22float2(p[j]);
        acc[2 * j] += f.x;
        acc[2 * j + 1] += f.y;
    }
}

// ================= slice-major fp16 layouts =================
// 128-col: H[((size_t)(k2>>1)*N + node)*2 + (k2&1)], k2 = uint4-col in [0,16)
// 64-col:  H[(size_t)k2*N + node], k2 in [0,8)

// ---------------- MFMA GEMM: slice-major in (or fp32 rows) / slice-major out ----------------

template<int MOUT, bool A_FP32>
__global__ __launch_bounds__(256) void k_gemm_mfmah(const void* __restrict__ Ain,
        const half8* __restrict__ Wp, const float* __restrict__ dinv,
        __half* __restrict__ out, int n) {
    constexpr int NT = MOUT / 16;
    constexpr int TPW = NT / 4;
    constexpr int LDR = 136;
    __shared__ _Float16 As[64 * LDR];

    int row0 = blockIdx.x * 64;
    for (int idx = threadIdx.x; idx < 64 * 16; idx += 256) {
        int r = idx >> 4, k2 = idx & 15;
        int grow = row0 + r;
        half8 h = {};
        if (grow < n) {
            if constexpr (A_FP32) {
                const float* Af = (const float*)Ain;
                float4 va = *(const float4*)&Af[(size_t)grow * 128 + k2 * 8];
                float4 vb = *(const float4*)&Af[(size_t)grow * 128 + k2 * 8 + 4];
                h[0] = (_Float16)va.x; h[1] = (_Float16)va.y;
                h[2] = (_Float16)va.z; h[3] = (_Float16)va.w;
                h[4] = (_Float16)vb.x; h[5] = (_Float16)vb.y;
                h[6] = (_Float16)vb.z; h[7] = (_Float16)vb.w;
            } else {
                const uint4* A4 = (const uint4*)Ain;
                uint4 v = A4[((size_t)(k2 >> 1) * n + grow) * 2 + (k2 & 1)];
                h = *(half8*)&v;
            }
        }
        *(half8*)&As[r * LDR + k2 * 8] = h;
    }
    __syncthreads();

    int w = threadIdx.x >> 6, l = threadIdx.x & 63;
    int g = l >> 4, nn = l & 15;

    half8 xf[4][4];
    #pragma unroll
    for (int rg = 0; rg < 4; rg++)
        #pragma unroll
        for (int c = 0; c < 4; c++)
            xf[rg][c] = *(const half8*)&As[(16 * rg + nn) * LDR + (4 * c + g) * 8];

    f32x4 acc[4][TPW];
    #pragma unroll
    for (int rg = 0; rg < 4; rg++)
        #pragma unroll
        for (int tt = 0; tt < TPW; tt++)
            acc[rg][tt] = (f32x4){0.f, 0.f, 0.f, 0.f};

    #pragma unroll
    for (int tt = 0; tt < TPW; tt++) {
        int t = w * TPW + tt;
        #pragma unroll
        for (int c = 0; c < 4; c++) {
            half8 wh = Wp[(t * 4 + c) * 64 + l];
            half8 wl = Wp[NT * 4 * 64 + (t * 4 + c) * 64 + l];
            #pragma unroll
            for (int rg = 0; rg < 4; rg++) {
                acc[rg][tt] = __builtin_amdgcn_mfma_f32_16x16x32_f16(wh, xf[rg][c], acc[rg][tt], 0, 0, 0);
                acc[rg][tt] = __builtin_amdgcn_mfma_f32_16x16x32_f16(wl, xf[rg][c], acc[rg][tt], 0, 0, 0);
            }
        }
    }

    __syncthreads();
    #pragma unroll
    for (int rg = 0; rg < 4; rg++) {
        int node = row0 + 16 * rg + nn;
        float s = (node < n) ? dinv[node] : 0.f;
        #pragma unroll
        for (int tt = 0; tt < TPW; tt++) {
            int colh = 16 * (w * TPW + tt) + 4 * g;
            __half2 p0 = __float22half2_rn(make_float2(acc[rg][tt][0] * s, acc[rg][tt][1] * s));
            __half2 p1 = __float22half2_rn(make_float2(acc[rg][tt][2] * s, acc[rg][tt][3] * s));
            uint2 u;
            u.x = *(unsigned*)&p0;
            u.y = *(unsigned*)&p1;
            *(uint2*)&As[(16 * rg + nn) * LDR + colh] = u;
        }
    }
    __syncthreads();
    uint4* out4 = (uint4*)out;
    if constexpr (MOUT == 128) {
        for (int idx = threadIdx.x; idx < 64 * 16; idx += 256) {
            int r = idx >> 4, k2 = idx & 15;
            int grow = row0 + r;
            if (grow < n)
                out4[((size_t)(k2 >> 1) * n + grow) * 2 + (k2 & 1)] = *(const uint4*)&As[r * LDR + k2 * 8];
        }
    } else {  // 64
        for (int idx = threadIdx.x; idx < 64 * 8; idx += 256) {
            int r = idx >> 3, k2 = idx & 7;
            int grow = row0 + r;
            if (grow < n)
                out4[(size_t)k2 * n + grow] = *(const uint4*)&As[r * LDR + k2 * 8];
        }
    }
}

// ---------------- layer-5 GEMM: sliced-64 fp16 @ fp32 [64,2], scaled ----------------

__global__ void k_gemm5h(const __half* __restrict__ A, const float* __restrict__ W,
                         const float* __restrict__ dinv, float* __restrict__ out, int n) {
    __shared__ float Wl[128];
    if (threadIdx.x < 128) Wl[threadIdx.x] = W[threadIdx.x];
    __syncthreads();
    int i = blockIdx.x * blockDim.x + threadIdx.x;
    if (i >= n) return;
    const uint4* h4 = (const uint4*)A;
    float a0 = 0.f, a1 = 0.f;
    #pragma unroll
    for (int k2 = 0; k2 < 8; k2++) {
        uint4 v = h4[(size_t)k2 * n + i];
        const __half2* p = (const __half2*)&v;
        #pragma unroll
        for (int j = 0; j < 4; j++) {
            float2 x = __half22float2(p[j]);
            int k = k2 * 8 + 2 * j;
            a0 = fmaf(x.x, Wl[2 * k + 0], a0); a1 = fmaf(x.x, Wl[2 * k + 1], a1);
            a0 = fmaf(x.y, Wl[2 * k + 2], a0); a1 = fmaf(x.y, Wl[2 * k + 3], a1);
        }
    }
    float s = dinv[i];
    out[2 * i] = a0 * s;
    out[2 * i + 1] = a1 * s;
}

// ---------------- XCC-pinned work-stealing aggregation, slice-major in/out ----------------
// Each block reads its PHYSICAL XCD (HW_REG_XCC_ID) and drains the work counter
// of the matching slice (3.2MB region -> L2-resident), stealing only at the tail.

__global__ __launch_bounds__(256) void k_agg_x16(const __half* __restrict__ ht,
        const int* __restrict__ rowptr, const int* __restrict__ csr,
        const float* __restrict__ dinv, const float* __restrict__ bias,
        const float* __restrict__ gw, const float* __restrict__ bb,
        const float* __restrict__ rm, const float* __restrict__ rv,
        __half* __restrict__ out, int* __restrict__ wcnt, int n) {
    __shared__ int sIdx;
    const int nchunk = (n + 127) >> 7;
    int xcd = get_xcc();
    const uint4* h4 = (const uint4*)ht;
    int grp = threadIdx.x >> 1;      // node within chunk (0..127)
    int lc = threadIdx.x & 1;        // uint4 within 32B slice row
    for (int s = 0; s < 8; s++) {
        int sl = (xcd + s) & 7;
        const uint4* hs = h4 + (size_t)sl * n * 2;
        int c0 = sl * 16 + lc * 8;
        float4 b0 = *(const float4*)&bias[c0], b1 = *(const float4*)&bias[c0 + 4];
        float gv[8], bbv[8], rmv[8], rvv[8];
        *(float4*)&gv[0] = *(const float4*)&gw[c0];  *(float4*)&gv[4] = *(const float4*)&gw[c0 + 4];
        *(float4*)&bbv[0] = *(const float4*)&bb[c0]; *(float4*)&bbv[4] = *(const float4*)&bb[c0 + 4];
        *(float4*)&rmv[0] = *(const float4*)&rm[c0]; *(float4*)&rmv[4] = *(const float4*)&rm[c0 + 4];
        *(float4*)&rvv[0] = *(const float4*)&rv[c0]; *(float4*)&rvv[4] = *(const float4*)&rv[c0 + 4];
        for (;;) {
            if (threadIdx.x == 0) sIdx = atomicAdd(&wcnt[sl], 1);
            __syncthreads();
            int idx = sIdx;
            __syncthreads();
            if (idx >= nchunk) break;
            int i = idx * 128 + grp;
            if (i < n) {
                float acc[8] = {};
                h8_acc(acc, hs[(size_t)i * 2 + lc]);            // self loop
                int e1 = rowptr[i + 1];
                int e = rowptr[i];
                for (; e + 4 <= e1; e += 4) {
                    int s0 = csr[e], s1 = csr[e + 1], s2 = csr[e + 2], s3 = csr[e + 3];
                    uint4 v0 = hs[(size_t)s0 * 2 + lc];
                    uint4 v1 = hs[(size_t)s1 * 2 + lc];
                    uint4 v2 = hs[(size_t)s2 * 2 + lc];
                    uint4 v3 = hs[(size_t)s3 * 2 + lc];
                    h8_acc(acc, v0); h8_acc(acc, v1); h8_acc(acc, v2); h8_acc(acc, v3);
                }
                for (; e < e1; e++)
                    h8_acc(acc, hs[(size_t)csr[e] * 2 + lc]);

                float di = dinv[i];
                float o[8];
                o[0] = fmaf(acc[0], di, b0.x); o[1] = fmaf(acc[1], di, b0.y);
                o[2] = fmaf(acc[2], di, b0.z); o[3] = fmaf(acc[3], di, b0.w);
                o[4] = fmaf(acc[4], di, b1.x); o[5] = fmaf(acc[5], di, b1.y);
                o[6] = fmaf(acc[6], di, b1.z); o[7] = fmaf(acc[7], di, b1.w);
                #pragma unroll
                for (int j = 0; j < 8; j++)
                    o[j] = fmaxf(fmaf(o[j] - rmv[j], rsqrtf(rvv[j] + BN_EPS) * gv[j], bbv[j]), 0.f);
                __half2 q0 = __float22half2_rn(make_float2(o[0], o[1]));
                __half2 q1 = __float22half2_rn(make_float2(o[2], o[3]));
                __half2 q2 = __float22half2_rn(make_float2(o[4], o[5]));
                __half2 q3 = __float22half2_rn(make_float2(o[6], o[7]));
                uint4 u;
                u.x = *(unsigned*)&q0; u.y = *(unsigned*)&q1;
                u.z = *(unsigned*)&q2; u.w = *(unsigned*)&q3;
                ((uint4*)out)[((size_t)sl * n + i) * 2 + lc] = u;
            }
        }
    }
}

__global__ __launch_bounds__(256) void k_agg_x8(const __half* __restrict__ ht,
        const int* __restrict__ rowptr, const int* __restrict__ csr,
        const float* __restrict__ dinv, const float* __restrict__ bias,
        const float* __restrict__ gw, const float* __restrict__ bb,
        const float* __restrict__ rm, const float* __restrict__ rv,
        __half* __restrict__ out, int* __restrict__ wcnt, int n) {
    __shared__ int sIdx;
    const int nchunk = (n + 255) >> 8;
    int xcd = get_xcc();
    const uint4* h4 = (const uint4*)ht;
    for (int s = 0; s < 8; s++) {
        int sl = (xcd + s) & 7;
        const uint4* hs = h4 + (size_t)sl * n;
        int c0 = sl * 8;
        float4 b0 = *(const float4*)&bias[c0], b1 = *(const float4*)&bias[c0 + 4];
        float gv[8], bbv[8], rmv[8], rvv[8];
        *(float4*)&gv[0] = *(const float4*)&gw[c0];  *(float4*)&gv[4] = *(const float4*)&gw[c0 + 4];
        *(float4*)&bbv[0] = *(const float4*)&bb[c0]; *(float4*)&bbv[4] = *(const float4*)&bb[c0 + 4];
        *(float4*)&rmv[0] = *(const float4*)&rm[c0]; *(float4*)&rmv[4] = *(const float4*)&rm[c0 + 4];
        *(float4*)&rvv[0] = *(const float4*)&rv[c0]; *(float4*)&rvv[4] = *(const float4*)&rv[c0 + 4];
        for (;;) {
            if (threadIdx.x == 0) sIdx = atomicAdd(&wcnt[sl], 1);
            __syncthreads();
            int idx = sIdx;
            __syncthreads();
            if (idx >= nchunk) break;
            int i = idx * 256 + threadIdx.x;
            if (i < n) {
                float acc[8] = {};
                h8_acc(acc, hs[i]);
                int e1 = rowptr[i + 1];
                int e = rowptr[i];
                for (; e + 4 <= e1; e += 4) {
                    int s0 = csr[e], s1 = csr[e + 1], s2 = csr[e + 2], s3 = csr[e + 3];
                    uint4 v0 = hs[s0];
                    uint4 v1 = hs[s1];
                    uint4 v2 = hs[s2];
                    uint4 v3 = hs[s3];
                    h8_acc(acc, v0); h8_acc(acc, v1); h8_acc(acc, v2); h8_acc(acc, v3);
                }
                for (; e < e1; e++)
                    h8_acc(acc, hs[csr[e]]);

                float di = dinv[i];
                float o[8];
                o[0] = fmaf(acc[0], di, b0.x); o[1] = fmaf(acc[1], di, b0.y);
                o[2] = fmaf(acc[2], di, b0.z); o[3] = fmaf(acc[3], di, b0.w);
                o[4] = fmaf(acc[4], di, b1.x); o[5] = fmaf(acc[5], di, b1.y);
                o[6] = fmaf(acc[6], di, b1.z); o[7] = fmaf(acc[7], di, b1.w);
                #pragma unroll
                for (int j = 0; j < 8; j++)
                    o[j] = fmaxf(fmaf(o[j] - rmv[j], rsqrtf(rvv[j] + BN_EPS) * gv[j], bbv[j]), 0.f);
                __half2 q0 = __float22half2_rn(make_float2(o[0], o[1]));
                __half2 q1 = __float22half2_rn(make_float2(o[2], o[3]));
                __half2 q2 = __float22half2_rn(make_float2(o[4], o[5]));
                __half2 q3 = __float22half2_rn(make_float2(o[6], o[7]));
                uint4 u;
                u.x = *(unsigned*)&q0; u.y = *(unsigned*)&q1;
                u.z = *(unsigned*)&q2; u.w = *(unsigned*)&q3;
                ((uint4*)out)[(size_t)sl * n + i] = u;
            }
        }
    }
}

// ---------------- final aggregation over htS fp32 (800KB, cache-resident) ----------------

__global__ void k_agg_final(const float* __restrict__ ht, const int* __restrict__ rowptr,
                            const int* __restrict__ csr, const float* __restrict__ dinv,
                            const float* __restrict__ bias, float* __restrict__ out, int n) {
    int i = blockIdx.x * blockDim.x + threadIdx.x;
    if (i >= n) return;
    const float2* h2 = (const float2*)ht;
    float2 t = h2[i];
    float a0 = t.x, a1 = t.y;
    int e1 = rowptr[i + 1];
    int e = rowptr[i];
    for (; e + 4 <= e1; e += 4) {
        int s0 = csr[e], s1 = csr[e + 1], s2 = csr[e + 2], s3 = csr[e + 3];
        float2 u0 = h2[s0], u1 = h2[s1], u2 = h2[s2], u3 = h2[s3];
        a0 += (u0.x + u1.x) + (u2.x + u3.x);
        a1 += (u0.y + u1.y) + (u2.y + u3.y);
    }
    for (; e < e1; e++) {
        float2 u = h2[csr[e]];
        a0 += u.x; a1 += u.y;
    }
    float s = dinv[i];
    out[2 * i]     = fmaf(a0, s, bias[0]);
    out[2 * i + 1] = fmaf(a1, s, bias[1]);
}

// ---------------- launch ----------------

extern "C" void kernel_launch(void* const* d_in, const int* in_sizes, int n_in,
                              void* d_out, int out_size, void* d_ws, size_t ws_size,
                              hipStream_t stream) {
    const float* x  = (const float*)d_in[0];
    const int*   ei = (const int*)d_in[1];
    const float* W1 = (const float*)d_in[2];  const float* b1 = (const float*)d_in[3];
    const float* W2 = (const float*)d_in[4];  const float* b2 = (const float*)d_in[5];
    const float* W3 = (const float*)d_in[6];  const float* b3 = (const float*)d_in[7];
    const float* W4 = (const float*)d_in[8];  const float* b4 = (const float*)d_in[9];
    const float* W5 = (const float*)d_in[10]; const float* b5 = (const float*)d_in[11];
    const float* g1 = (const float*)d_in[12]; const float* be1 = (const float*)d_in[13];
    const float* rm1 = (const float*)d_in[14]; const float* rv1 = (const float*)d_in[15];
    const float* g2 = (const float*)d_in[16]; const float* be2 = (const float*)d_in[17];
    const float* rm2 = (const float*)d_in[18]; const float* rv2 = (const float*)d_in[19];
    const float* g3 = (const float*)d_in[20]; const float* be3 = (const float*)d_in[21];
    const float* rm3 = (const float*)d_in[22]; const float* rv3 = (const float*)d_in[23];
    const float* g4 = (const float*)d_in[24]; const float* be4 = (const float*)d_in[25];
    const float* rm4 = (const float*)d_in[26]; const float* rv4 = (const float*)d_in[27];

    const int N = in_sizes[0] / 128;
    const int E = in_sizes[1] / 2;
    const int* src = ei;
    const int* dst = ei + E;
    const int nbk = (N + 255) >> 8;

    char* base = (char*)d_ws;
    size_t off = 0;
    auto carve = [&](size_t bytes) -> void* {
        void* r = base + off;
        off = (off + bytes + 255) & ~(size_t)255;
        return r;
    };
    __half* htA = (__half*)carve((size_t)N * 128 * 2);
    __half* htB = (__half*)carve((size_t)N * 128 * 2);
    float*  htS = (float*)carve((size_t)N * 2 * 4);
    half8*  Wp1 = (half8*)carve(2 * 8 * 4 * 64 * 16);
    half8*  Wp2 = (half8*)carve(2 * 8 * 4 * 64 * 16);
    half8*  Wp3 = (half8*)carve(2 * 8 * 4 * 64 * 16);
    half8*  Wp4 = (half8*)carve(2 * 4 * 4 * 64 * 16);
    unsigned* pairs = (unsigned*)carve((size_t)MAXBKT * CAP * 4);
    int*   bucket_cur = (int*)carve((size_t)MAXBKT * 4);
    int*   wcnt  = (int*)carve(32 * 4);
    int*   rowptr= (int*)carve((size_t)(N + 1) * 4);
    int*   csr   = (int*)carve((size_t)E * 4);
    float* dinv  = (float*)carve((size_t)N * 4);
    int*   bsums = (int*)carve((size_t)nbk * 4);
    (void)ws_size; (void)n_in; (void)out_size;

    float* out = (float*)d_out;

    // weight packs
    k_wpack<128><<<8, 256, 0, stream>>>(W1, Wp1);
    k_wpack<128><<<8, 256, 0, stream>>>(W2, Wp2);
    k_wpack<128><<<8, 256, 0, stream>>>(W3, Wp3);
    k_wpack<64><<<4, 256, 0, stream>>>(W4, Wp4);

    // bucketed CSR build + degree
    k_init   <<<(N + 255) / 256, 256, 0, stream>>>(bucket_cur, wcnt, rowptr, N, E);
    k_bin    <<<(E + 2047) / 2048, 256, 0, stream>>>(src, dst, E, nbk, bucket_cur, pairs);
    k_cntscan<<<nbk, 256, 0, stream>>>(pairs, bucket_cur, rowptr, bsums, dinv, N);
    k_scan2  <<<1, 1024, 0, stream>>>(bsums, nbk);
    k_scan3  <<<(N + 255) / 256, 256, 0, stream>>>(rowptr, bsums, N);
    k_fill2  <<<nbk, 256, 0, stream>>>(pairs, bucket_cur, rowptr, csr, N);

    const int gb = (N + 63) / 64;
    const int ga = 2048;   // persistent work-stealing agg grid

    // layer 1
    k_gemm_mfmah<128, true><<<gb, 256, 0, stream>>>(x, Wp1, dinv, htA, N);
    k_agg_x16<<<ga, 256, 0, stream>>>(htA, rowptr, csr, dinv, b1, g1, be1, rm1, rv1, htB, wcnt + 0, N);
    // layer 2
    k_gemm_mfmah<128, false><<<gb, 256, 0, stream>>>(htB, Wp2, dinv, htA, N);
    k_agg_x16<<<ga, 256, 0, stream>>>(htA, rowptr, csr, dinv, b2, g2, be2, rm2, rv2, htB, wcnt + 8, N);
    // layer 3
    k_gemm_mfmah<128, false><<<gb, 256, 0, stream>>>(htB, Wp3, dinv, htA, N);
    k_agg_x16<<<ga, 256, 0, stream>>>(htA, rowptr, csr, dinv, b3, g3, be3, rm3, rv3, htB, wcnt + 16, N);
    // layer 4: 128 -> 64
    k_gemm_mfmah<64, false><<<gb, 256, 0, stream>>>(htB, Wp4, dinv, htA, N);
    k_agg_x8<<<ga, 256, 0, stream>>>(htA, rowptr, csr, dinv, b4, g4, be4, rm4, rv4, htB, wcnt + 24, N);
    // layer 5: 64 -> 2
    k_gemm5h<<<(N + 255) / 256, 256, 0, stream>>>(htB, W5, dinv, htS, N);
    k_agg_final<<<(N + 255) / 256, 256, 0, stream>>>(htS, rowptr, csr, dinv, b5, out, N);
}

// Round 10
// 422.527 us; speedup vs baseline: 2.9597x; 2.9597x over previous
//
#include <hip/hip_runtime.h>
#include <hip/hip_fp16.h>

#define BN_EPS 1e-5f
#define CAP 8192        // max edges per bucket (mean ~4092; 2x headroom)
#define MAXBKT 512      // supports N up to 131072 (src must fit 24 bits)

typedef _Float16 half8 __attribute__((ext_vector_type(8)));
typedef float f32x4 __attribute__((ext_vector_type(4)));

// ---------------- bucketed CSR build (packed: src | dstlo<<24) ----------------

__global__ void k_init(int* bucket_cur, int* rowptr, int n, int E) {
    int i = blockIdx.x * blockDim.x + threadIdx.x;
    if (i < MAXBKT) bucket_cur[i] = 0;
    if (i == 0) rowptr[n] = E;
}

__global__ __launch_bounds__(256) void k_bin(const int* __restrict__ src,
        const int* __restrict__ dst, int E, int nbk,
        int* __restrict__ bucket_cur, unsigned* __restrict__ pairs) {
    __shared__ int hist[MAXBKT];
    __shared__ int base_[MAXBKT];
    for (int b = threadIdx.x; b < nbk; b += 256) hist[b] = 0;
    __syncthreads();
    int e0 = blockIdx.x * 2048;
    int my_b[8], my_l[8];
    unsigned my_p[8];
    #pragma unroll
    for (int j = 0; j < 8; j++) {
        int e = e0 + threadIdx.x + j * 256;
        my_b[j] = -1;
        if (e < E) {
            int d = dst[e];
            my_p[j] = (unsigned)src[e] | ((unsigned)(d & 255) << 24);
            my_b[j] = d >> 8;
            my_l[j] = atomicAdd(&hist[my_b[j]], 1);
        }
    }
    __syncthreads();
    for (int b = threadIdx.x; b < nbk; b += 256) {
        int h = hist[b];
        base_[b] = h ? atomicAdd(&bucket_cur[b], h) : 0;
    }
    __syncthreads();
    #pragma unroll
    for (int j = 0; j < 8; j++) {
        if (my_b[j] >= 0) {
            int pos = base_[my_b[j]] + my_l[j];
            if (pos < CAP)
                pairs[(size_t)my_b[j] * CAP + pos] = my_p[j];
        }
    }
}

// per-bucket: degree hist + block-exclusive-scan + dinv (one pass over pairs)
__global__ __launch_bounds__(256) void k_cntscan(const unsigned* __restrict__ pairs,
        const int* __restrict__ bucket_cur, int* __restrict__ rowptr,
        int* __restrict__ bsums, float* __restrict__ dinv, int n) {
    __shared__ int lc[256];
    __shared__ int tmp[256];
    lc[threadIdx.x] = 0;
    __syncthreads();
    int b = blockIdx.x;
    int m = min(bucket_cur[b], CAP);
    const unsigned* p = pairs + (size_t)b * CAP;
    for (int q = threadIdx.x; q < m; q += 256)
        atomicAdd(&lc[p[q] >> 24], 1);
    __syncthreads();
    int v = lc[threadIdx.x];
    tmp[threadIdx.x] = v;
    __syncthreads();
    for (int off = 1; off < 256; off <<= 1) {
        int t = (threadIdx.x >= off) ? tmp[threadIdx.x - off] : 0;
        __syncthreads();
        tmp[threadIdx.x] += t;
        __syncthreads();
    }
    int node = b * 256 + threadIdx.x;
    if (node < n) {
        rowptr[node] = tmp[threadIdx.x] - v;   // bucket-local exclusive
        dinv[node] = rsqrtf((float)v + 1.0f);
    }
    if (threadIdx.x == 255) bsums[b] = tmp[255];
}

__global__ void k_scan2(int* bsums, int nb) {
    __shared__ int tmp[1024];
    int v = (threadIdx.x < nb) ? bsums[threadIdx.x] : 0;
    tmp[threadIdx.x] = v;
    __syncthreads();
    for (int off = 1; off < 1024; off <<= 1) {
        int t = (threadIdx.x >= off) ? tmp[threadIdx.x - off] : 0;
        __syncthreads();
        tmp[threadIdx.x] += t;
        __syncthreads();
    }
    if (threadIdx.x < nb) bsums[threadIdx.x] = tmp[threadIdx.x] - v;  // exclusive
}

__global__ void k_scan3(int* __restrict__ rowptr, const int* __restrict__ bsums, int n) {
    int i = blockIdx.x * blockDim.x + threadIdx.x;
    if (i < n) rowptr[i] += bsums[i >> 8];
}

__global__ __launch_bounds__(256) void k_fill2(const unsigned* __restrict__ pairs,
        const int* __restrict__ bucket_cur, const int* __restrict__ rowptr,
        int* __restrict__ csr, int n) {
    __shared__ int cur[256];
    __shared__ int stg[CAP];
    int b = blockIdx.x;
    int node0 = b * 256;
    int nend = min(node0 + 256, n);
    int base_csr = rowptr[node0];
    int node = node0 + threadIdx.x;
    cur[threadIdx.x] = (node < n) ? rowptr[node] - base_csr : 0;
    __syncthreads();
    int m = min(bucket_cur[b], CAP);
    const unsigned* p = pairs + (size_t)b * CAP;
    for (int q = threadIdx.x; q < m; q += 256) {
        unsigned pr = p[q];
        int ofs = atomicAdd(&cur[pr >> 24], 1);
        stg[ofs] = (int)(pr & 0xFFFFFFu);
    }
    __syncthreads();
    int len = rowptr[nend] - base_csr;
    for (int q = threadIdx.x; q < len; q += 256)
        csr[base_csr + q] = stg[q];
}

// ---------------- W pack: fp32 [128][M] -> fp16 hi/lo lane fragments ----------------

template<int M>
__global__ void k_wpack(const float* __restrict__ W, half8* __restrict__ Wp) {
    int idx = blockIdx.x * 256 + threadIdx.x;
    constexpr int TOT = (M / 16) * 4 * 64;
    if (idx >= TOT) return;
    int l = idx & 63, tc = idx >> 6;
    int c = tc & 3, t = tc >> 2;
    int g = l >> 4, nn = l & 15;
    int k0 = 32 * c + 8 * g, col = 16 * t + nn;
    half8 hi, lo;
    #pragma unroll
    for (int j = 0; j < 8; j++) {
        float w = W[(size_t)(k0 + j) * M + col];
        _Float16 h = (_Float16)w;
        hi[j] = h;
        lo[j] = (_Float16)(w - (float)h);
    }
    Wp[idx] = hi;
    Wp[TOT + idx] = lo;
}

// ---------------- helpers ----------------

__device__ __forceinline__ void h8_acc(float* acc, uint4 v) {
    const __half2* p = (const __half2*)&v;
    #pragma unroll
    for (int j = 0; j < 4; j++) {
        float2 f = __half22float2(p[j]);
        acc[2 * j] += f.x;
        acc[2 * j + 1] += f.y;
    }
}

// ---------------- layer-1 GEMM: ht16 = half( (x @ W1) * dinv ) ----------------

__global__ __launch_bounds__(256) void k_gemm_mfma1(const float* __restrict__ Ain,
        const half8* __restrict__ Wp, const float* __restrict__ dinv,
        __half* __restrict__ out, int n) {
    constexpr int LDR = 136;
    __shared__ _Float16 As[64 * LDR];

    int row0 = blockIdx.x * 64;
    for (int idx = threadIdx.x; idx < 64 * 16; idx += 256) {
        int r = idx >> 4, k2 = idx & 15;
        int grow = row0 + r;
        half8 h = {};
        if (grow < n) {
            float4 va = *(const float4*)&Ain[(size_t)grow * 128 + k2 * 8];
            float4 vb = *(const float4*)&Ain[(size_t)grow * 128 + k2 * 8 + 4];
            h[0] = (_Float16)va.x; h[1] = (_Float16)va.y;
            h[2] = (_Float16)va.z; h[3] = (_Float16)va.w;
            h[4] = (_Float16)vb.x; h[5] = (_Float16)vb.y;
            h[6] = (_Float16)vb.z; h[7] = (_Float16)vb.w;
        }
        *(half8*)&As[r * LDR + k2 * 8] = h;
    }
    __syncthreads();

    int w = threadIdx.x >> 6, l = threadIdx.x & 63;
    int g = l >> 4, nn = l & 15;

    half8 xf[4][4];
    #pragma unroll
    for (int rg = 0; rg < 4; rg++)
        #pragma unroll
        for (int c = 0; c < 4; c++)
            xf[rg][c] = *(const half8*)&As[(16 * rg + nn) * LDR + (4 * c + g) * 8];

    f32x4 acc[4][2];
    #pragma unroll
    for (int rg = 0; rg < 4; rg++)
        #pragma unroll
        for (int tt = 0; tt < 2; tt++)
            acc[rg][tt] = (f32x4){0.f, 0.f, 0.f, 0.f};

    #pragma unroll
    for (int tt = 0; tt < 2; tt++) {
        int t = w * 2 + tt;
        #pragma unroll
        for (int c = 0; c < 4; c++) {
            half8 wh = Wp[(t * 4 + c) * 64 + l];
            half8 wl = Wp[8 * 4 * 64 + (t * 4 + c) * 64 + l];
            #pragma unroll
            for (int rg = 0; rg < 4; rg++) {
                acc[rg][tt] = __builtin_amdgcn_mfma_f32_16x16x32_f16(wh, xf[rg][c], acc[rg][tt], 0, 0, 0);
                acc[rg][tt] = __builtin_amdgcn_mfma_f32_16x16x32_f16(wl, xf[rg][c], acc[rg][tt], 0, 0, 0);
            }
        }
    }

    __syncthreads();
    #pragma unroll
    for (int rg = 0; rg < 4; rg++) {
        int node = row0 + 16 * rg + nn;
        float s = (node < n) ? dinv[node] : 0.f;
        #pragma unroll
        for (int tt = 0; tt < 2; tt++) {
            int colh = 16 * (w * 2 + tt) + 4 * g;
            __half2 p0 = __float22half2_rn(make_float2(acc[rg][tt][0] * s, acc[rg][tt][1] * s));
            __half2 p1 = __float22half2_rn(make_float2(acc[rg][tt][2] * s, acc[rg][tt][3] * s));
            uint2 u;
            u.x = *(unsigned*)&p0;
            u.y = *(unsigned*)&p1;
            *(uint2*)&As[(16 * rg + nn) * LDR + colh] = u;
        }
    }
    __syncthreads();
    for (int idx = threadIdx.x; idx < 64 * 16; idx += 256) {
        int r = idx >> 4, k2 = idx & 15;
        int grow = row0 + r;
        if (grow < n)
            *(uint4*)&out[(size_t)grow * 128 + k2 * 8] = *(const uint4*)&As[r * LDR + k2 * 8];
    }
}

// ---------------- fused: agg_l (+bias+BN+ReLU) -> LDS -> GEMM_{l+1} ----------------
// Input ht: [n,128] fp16 row-major (dinv-scaled). Output: [n,MOUT] fp16 (dinv-scaled).
// Edge loop unrolled x8: 8 idx + 8 uint4 row-gathers in flight per lane.

template<int MOUT>
__global__ __launch_bounds__(256) void k_fused_mfma(const __half* __restrict__ ht,
        const int* __restrict__ rowptr, const int* __restrict__ csr,
        const float* __restrict__ dinv, const float* __restrict__ bias,
        const float* __restrict__ gw, const float* __restrict__ bb,
        const float* __restrict__ rm, const float* __restrict__ rv,
        const half8* __restrict__ Wp, __half* __restrict__ out, int n) {
    constexpr int NT = MOUT / 16;
    constexpr int TPW = NT / 4;
    constexpr int LDR = 136;
    __shared__ _Float16 As[64 * LDR];

    int row0 = blockIdx.x * 64;
    int grp = threadIdx.x >> 4;      // 0..15: node within pass
    int c = threadIdx.x & 15;        // uint4 index within 128-col row
    const uint4* h4 = (const uint4*)ht;
    int c0 = c * 8;
    float4 bv0 = *(const float4*)&bias[c0], bv1 = *(const float4*)&bias[c0 + 4];
    float gv[8], bbv[8], rmv[8], rvv[8];
    *(float4*)&gv[0] = *(const float4*)&gw[c0];  *(float4*)&gv[4] = *(const float4*)&gw[c0 + 4];
    *(float4*)&bbv[0] = *(const float4*)&bb[c0]; *(float4*)&bbv[4] = *(const float4*)&bb[c0 + 4];
    *(float4*)&rmv[0] = *(const float4*)&rm[c0]; *(float4*)&rmv[4] = *(const float4*)&rm[c0 + 4];
    *(float4*)&rvv[0] = *(const float4*)&rv[c0]; *(float4*)&rvv[4] = *(const float4*)&rv[c0 + 4];

    // ---- Phase A: aggregate + BN + ReLU for 64 nodes (4 passes of 16) ----
    for (int p = 0; p < 4; p++) {
        int r = p * 16 + grp;
        int i = row0 + r;
        uint4 u = make_uint4(0, 0, 0, 0);
        if (i < n) {
            float acc[8] = {};
            h8_acc(acc, h4[(size_t)i * 16 + c]);   // self loop
            int e1 = rowptr[i + 1];
            int e = rowptr[i];
            for (; e + 8 <= e1; e += 8) {
                int s0 = csr[e],     s1 = csr[e + 1], s2 = csr[e + 2], s3 = csr[e + 3];
                int s4 = csr[e + 4], s5 = csr[e + 5], s6 = csr[e + 6], s7 = csr[e + 7];
                uint4 v0 = h4[(size_t)s0 * 16 + c];
                uint4 v1 = h4[(size_t)s1 * 16 + c];
                uint4 v2 = h4[(size_t)s2 * 16 + c];
                uint4 v3 = h4[(size_t)s3 * 16 + c];
                uint4 v4 = h4[(size_t)s4 * 16 + c];
                uint4 v5 = h4[(size_t)s5 * 16 + c];
                uint4 v6 = h4[(size_t)s6 * 16 + c];
                uint4 v7 = h4[(size_t)s7 * 16 + c];
                h8_acc(acc, v0); h8_acc(acc, v1); h8_acc(acc, v2); h8_acc(acc, v3);
                h8_acc(acc, v4); h8_acc(acc, v5); h8_acc(acc, v6); h8_acc(acc, v7);
            }
            for (; e < e1; e++)
                h8_acc(acc, h4[(size_t)csr[e] * 16 + c]);
            float di = dinv[i];
            float o[8];
            o[0] = fmaf(acc[0], di, bv0.x); o[1] = fmaf(acc[1], di, bv0.y);
            o[2] = fmaf(acc[2], di, bv0.z); o[3] = fmaf(acc[3], di, bv0.w);
            o[4] = fmaf(acc[4], di, bv1.x); o[5] = fmaf(acc[5], di, bv1.y);
            o[6] = fmaf(acc[6], di, bv1.z); o[7] = fmaf(acc[7], di, bv1.w);
            #pragma unroll
            for (int j = 0; j < 8; j++)
                o[j] = fmaxf(fmaf(o[j] - rmv[j], rsqrtf(rvv[j] + BN_EPS) * gv[j], bbv[j]), 0.f);
            __half2 q0 = __float22half2_rn(make_float2(o[0], o[1]));
            __half2 q1 = __float22half2_rn(make_float2(o[2], o[3]));
            __half2 q2 = __float22half2_rn(make_float2(o[4], o[5]));
            __half2 q3 = __float22half2_rn(make_float2(o[6], o[7]));
            u.x = *(unsigned*)&q0; u.y = *(unsigned*)&q1;
            u.z = *(unsigned*)&q2; u.w = *(unsigned*)&q3;
        }
        *(uint4*)&As[r * LDR + c0] = u;
    }
    __syncthreads();

    // ---- Phase B: MFMA GEMM from LDS ----
    int w = threadIdx.x >> 6, l = threadIdx.x & 63;
    int g = l >> 4, nn = l & 15;

    half8 xf[4][4];
    #pragma unroll
    for (int rg = 0; rg < 4; rg++)
        #pragma unroll
        for (int cc = 0; cc < 4; cc++)
            xf[rg][cc] = *(const half8*)&As[(16 * rg + nn) * LDR + (4 * cc + g) * 8];

    f32x4 acc2[4][TPW];
    #pragma unroll
    for (int rg = 0; rg < 4; rg++)
        #pragma unroll
        for (int tt = 0; tt < TPW; tt++)
            acc2[rg][tt] = (f32x4){0.f, 0.f, 0.f, 0.f};

    #pragma unroll
    for (int tt = 0; tt < TPW; tt++) {
        int t = w * TPW + tt;
        #pragma unroll
        for (int cc = 0; cc < 4; cc++) {
            half8 wh = Wp[(t * 4 + cc) * 64 + l];
            half8 wl = Wp[NT * 4 * 64 + (t * 4 + cc) * 64 + l];
            #pragma unroll
            for (int rg = 0; rg < 4; rg++) {
                acc2[rg][tt] = __builtin_amdgcn_mfma_f32_16x16x32_f16(wh, xf[rg][cc], acc2[rg][tt], 0, 0, 0);
                acc2[rg][tt] = __builtin_amdgcn_mfma_f32_16x16x32_f16(wl, xf[rg][cc], acc2[rg][tt], 0, 0, 0);
            }
        }
    }

    __syncthreads();
    #pragma unroll
    for (int rg = 0; rg < 4; rg++) {
        int node = row0 + 16 * rg + nn;
        float s = (node < n) ? dinv[node] : 0.f;
        #pragma unroll
        for (int tt = 0; tt < TPW; tt++) {
            int colh = 16 * (w * TPW + tt) + 4 * g;
            __half2 p0 = __float22half2_rn(make_float2(acc2[rg][tt][0] * s, acc2[rg][tt][1] * s));
            __half2 p1 = __float22half2_rn(make_float2(acc2[rg][tt][2] * s, acc2[rg][tt][3] * s));
            uint2 uu;
            uu.x = *(unsigned*)&p0;
            uu.y = *(unsigned*)&p1;
            *(uint2*)&As[(16 * rg + nn) * LDR + colh] = uu;
        }
    }
    __syncthreads();
    for (int idx = threadIdx.x; idx < 64 * (MOUT / 8); idx += 256) {
        int r = idx / (MOUT / 8), k2 = idx % (MOUT / 8);
        int grow = row0 + r;
        if (grow < n)
            *(uint4*)&out[(size_t)grow * MOUT + k2 * 8] = *(const uint4*)&As[r * LDR + k2 * 8];
    }
}

// ---------------- fused: agg4 (64-col, +BN+ReLU) -> GEMM5 [64,2] -> htS fp32 ----------------

__global__ __launch_bounds__(256) void k_fused5(const __half* __restrict__ ht,
        const int* __restrict__ rowptr, const int* __restrict__ csr,
        const float* __restrict__ dinv, const float* __restrict__ bias,
        const float* __restrict__ gw, const float* __restrict__ bb,
        const float* __restrict__ rm, const float* __restrict__ rv,
        const float* __restrict__ W5, float* __restrict__ outS, int n) {
    constexpr int LDR = 72;
    __shared__ _Float16 As[64 * LDR];
    __shared__ float Wl[128];
    if (threadIdx.x < 128) Wl[threadIdx.x] = W5[threadIdx.x];

    int row0 = blockIdx.x * 64;
    int grp = threadIdx.x >> 3;      // 0..31: node within pass
    int c = threadIdx.x & 7;         // uint4 index within 64-col row
    const uint4* h4 = (const uint4*)ht;
    int c0 = c * 8;
    float4 bv0 = *(const float4*)&bias[c0], bv1 = *(const float4*)&bias[c0 + 4];
    float gv[8], bbv[8], rmv[8], rvv[8];
    *(float4*)&gv[0] = *(const float4*)&gw[c0];  *(float4*)&gv[4] = *(const float4*)&gw[c0 + 4];
    *(float4*)&bbv[0] = *(const float4*)&bb[c0]; *(float4*)&bbv[4] = *(const float4*)&bb[c0 + 4];
    *(float4*)&rmv[0] = *(const float4*)&rm[c0]; *(float4*)&rmv[4] = *(const float4*)&rm[c0 + 4];
    *(float4*)&rvv[0] = *(const float4*)&rv[c0]; *(float4*)&rvv[4] = *(const float4*)&rv[c0 + 4];

    for (int p = 0; p < 2; p++) {
        int r = p * 32 + grp;
        int i = row0 + r;
        uint4 u = make_uint4(0, 0, 0, 0);
        if (i < n) {
            float acc[8] = {};
            h8_acc(acc, h4[(size_t)i * 8 + c]);
            int e1 = rowptr[i + 1];
            int e = rowptr[i];
            for (; e + 8 <= e1; e += 8) {
                int s0 = csr[e],     s1 = csr[e + 1], s2 = csr[e + 2], s3 = csr[e + 3];
                int s4 = csr[e + 4], s5 = csr[e + 5], s6 = csr[e + 6], s7 = csr[e + 7];
                uint4 v0 = h4[(size_t)s0 * 8 + c];
                uint4 v1 = h4[(size_t)s1 * 8 + c];
                uint4 v2 = h4[(size_t)s2 * 8 + c];
                uint4 v3 = h4[(size_t)s3 * 8 + c];
                uint4 v4 = h4[(size_t)s4 * 8 + c];
                uint4 v5 = h4[(size_t)s5 * 8 + c];
                uint4 v6 = h4[(size_t)s6 * 8 + c];
                uint4 v7 = h4[(size_t)s7 * 8 + c];
                h8_acc(acc, v0); h8_acc(acc, v1); h8_acc(acc, v2); h8_acc(acc, v3);
                h8_acc(acc, v4); h8_acc(acc, v5); h8_acc(acc, v6); h8_acc(acc, v7);
            }
            for (; e < e1; e++)
                h8_acc(acc, h4[(size_t)csr[e] * 8 + c]);
            float di = dinv[i];
            float o[8];
            o[0] = fmaf(acc[0], di, bv0.x); o[1] = fmaf(acc[1], di, bv0.y);
            o[2] = fmaf(acc[2], di, bv0.z); o[3] = fmaf(acc[3], di, bv0.w);
            o[4] = fmaf(acc[4], di, bv1.x); o[5] = fmaf(acc[5], di, bv1.y);
            o[6] = fmaf(acc[6], di, bv1.z); o[7] = fmaf(acc[7], di, bv1.w);
            #pragma unroll
            for (int j = 0; j < 8; j++)
                o[j] = fmaxf(fmaf(o[j] - rmv[j], rsqrtf(rvv[j] + BN_EPS) * gv[j], bbv[j]), 0.f);
            __half2 q0 = __float22half2_rn(make_float2(o[0], o[1]));
            __half2 q1 = __float22half2_rn(make_float2(o[2], o[3]));
            __half2 q2 = __float22half2_rn(make_float2(o[4], o[5]));
            __half2 q3 = __float22half2_rn(make_float2(o[6], o[7]));
            u.x = *(unsigned*)&q0; u.y = *(unsigned*)&q1;
            u.z = *(unsigned*)&q2; u.w = *(unsigned*)&q3;
        }
        *(uint4*)&As[r * LDR + c0] = u;
    }
    __syncthreads();

    if (threadIdx.x < 128) {
        int r = threadIdx.x >> 1, cls = threadIdx.x & 1;
        int i = row0 + r;
        if (i < n) {
            float a = 0.f;
            const __half2* row = (const __half2*)&As[r * LDR];
            #pragma unroll
            for (int k2 = 0; k2 < 32; k2++) {
                float2 xx = __half22float2(row[k2]);
                a = fmaf(xx.x, Wl[4 * k2 + cls], a);
                a = fmaf(xx.y, Wl[4 * k2 + 2 + cls], a);
            }
            outS[2 * i + cls] = a * dinv[i];
        }
    }
}

// ---------------- final aggregation over htS fp32 (800KB, cache-resident) ----------------

__global__ void k_agg_final(const float* __restrict__ ht, const int* __restrict__ rowptr,
                            const int* __restrict__ csr, const float* __restrict__ dinv,
                            const float* __restrict__ bias, float* __restrict__ out, int n) {
    int i = blockIdx.x * blockDim.x + threadIdx.x;
    if (i >= n) return;
    const float2* h2 = (const float2*)ht;
    float2 t = h2[i];
    float a0 = t.x, a1 = t.y;
    int e1 = rowptr[i + 1];
    int e = rowptr[i];
    for (; e + 4 <= e1; e += 4) {
        int s0 = csr[e], s1 = csr[e + 1], s2 = csr[e + 2], s3 = csr[e + 3];
        float2 u0 = h2[s0], u1 = h2[s1], u2 = h2[s2], u3 = h2[s3];
        a0 += (u0.x + u1.x) + (u2.x + u3.x);
        a1 += (u0.y + u1.y) + (u2.y + u3.y);
    }
    for (; e < e1; e++) {
        float2 u = h2[csr[e]];
        a0 += u.x; a1 += u.y;
    }
    float s = dinv[i];
    out[2 * i]     = fmaf(a0, s, bias[0]);
    out[2 * i + 1] = fmaf(a1, s, bias[1]);
}

// ---------------- launch ----------------

extern "C" void kernel_launch(void* const* d_in, const int* in_sizes, int n_in,
                              void* d_out, int out_size, void* d_ws, size_t ws_size,
                              hipStream_t stream) {
    const float* x  = (const float*)d_in[0];
    const int*   ei = (const int*)d_in[1];
    const float* W1 = (const float*)d_in[2];  const float* b1 = (const float*)d_in[3];
    const float* W2 = (const float*)d_in[4];  const float* b2 = (const float*)d_in[5];
    const float* W3 = (const float*)d_in[6];  const float* b3 = (const float*)d_in[7];
    const float* W4 = (const float*)d_in[8];  const float* b4 = (const float*)d_in[9];
    const float* W5 = (const float*)d_in[10]; const float* b5 = (const float*)d_in[11];
    const float* g1 = (const float*)d_in[12]; const float* be1 = (const float*)d_in[13];
    const float* rm1 = (const float*)d_in[14]; const float* rv1 = (const float*)d_in[15];
    const float* g2 = (const float*)d_in[16]; const float* be2 = (const float*)d_in[17];
    const float* rm2 = (const float*)d_in[18]; const float* rv2 = (const float*)d_in[19];
    const float* g3 = (const float*)d_in[20]; const float* be3 = (const float*)d_in[21];
    const float* rm3 = (const float*)d_in[22]; const float* rv3 = (const float*)d_in[23];
    const float* g4 = (const float*)d_in[24]; const float* be4 = (const float*)d_in[25];
    const float* rm4 = (const float*)d_in[26]; const float* rv4 = (const float*)d_in[27];

    const int N = in_sizes[0] / 128;
    const int E = in_sizes[1] / 2;
    const int* src = ei;
    const int* dst = ei + E;
    const int nbk = (N + 255) >> 8;

    char* base = (char*)d_ws;
    size_t off = 0;
    auto carve = [&](size_t bytes) -> void* {
        void* r = base + off;
        off = (off + bytes + 255) & ~(size_t)255;
        return r;
    };
    __half* htA = (__half*)carve((size_t)N * 128 * 2);
    __half* htB = (__half*)carve((size_t)N * 128 * 2);
    float*  htS = (float*)carve((size_t)N * 2 * 4);
    half8*  Wp1 = (half8*)carve(2 * 8 * 4 * 64 * 16);
    half8*  Wp2 = (half8*)carve(2 * 8 * 4 * 64 * 16);
    half8*  Wp3 = (half8*)carve(2 * 8 * 4 * 64 * 16);
    half8*  Wp4 = (half8*)carve(2 * 4 * 4 * 64 * 16);
    unsigned* pairs = (unsigned*)carve((size_t)MAXBKT * CAP * 4);
    int*   bucket_cur = (int*)carve((size_t)MAXBKT * 4);
    int*   rowptr= (int*)carve((size_t)(N + 1) * 4);
    int*   csr   = (int*)carve((size_t)E * 4);
    float* dinv  = (float*)carve((size_t)N * 4);
    int*   bsums = (int*)carve((size_t)nbk * 4);
    (void)ws_size; (void)n_in; (void)out_size;

    float* out = (float*)d_out;

    // weight packs
    k_wpack<128><<<8, 256, 0, stream>>>(W1, Wp1);
    k_wpack<128><<<8, 256, 0, stream>>>(W2, Wp2);
    k_wpack<128><<<8, 256, 0, stream>>>(W3, Wp3);
    k_wpack<64><<<4, 256, 0, stream>>>(W4, Wp4);

    // bucketed CSR build + degree
    k_init   <<<(N + 255) / 256, 256, 0, stream>>>(bucket_cur, rowptr, N, E);
    k_bin    <<<(E + 2047) / 2048, 256, 0, stream>>>(src, dst, E, nbk, bucket_cur, pairs);
    k_cntscan<<<nbk, 256, 0, stream>>>(pairs, bucket_cur, rowptr, bsums, dinv, N);
    k_scan2  <<<1, 1024, 0, stream>>>(bsums, nbk);
    k_scan3  <<<(N + 255) / 256, 256, 0, stream>>>(rowptr, bsums, N);
    k_fill2  <<<nbk, 256, 0, stream>>>(pairs, bucket_cur, rowptr, csr, N);

    const int gb = (N + 63) / 64;
    // layer 1 GEMM
    k_gemm_mfma1<<<gb, 256, 0, stream>>>(x, Wp1, dinv, htA, N);
    // fused agg1 + GEMM2
    k_fused_mfma<128><<<gb, 256, 0, stream>>>(htA, rowptr, csr, dinv, b1, g1, be1, rm1, rv1, Wp2, htB, N);
    // fused agg2 + GEMM3
    k_fused_mfma<128><<<gb, 256, 0, stream>>>(htB, rowptr, csr, dinv, b2, g2, be2, rm2, rv2, Wp3, htA, N);
    // fused agg3 + GEMM4 (128 -> 64)
    k_fused_mfma<64><<<gb, 256, 0, stream>>>(htA, rowptr, csr, dinv, b3, g3, be3, rm3, rv3, Wp4, htB, N);
    // fused agg4 + GEMM5 (64 -> 2)
    k_fused5<<<gb, 256, 0, stream>>>(htB, rowptr, csr, dinv, b4, g4, be4, rm4, rv4, W5, htS, N);
    // final aggregation
    k_agg_final<<<(N + 255) / 256, 256, 0, stream>>>(htS, rowptr, csr, dinv, b5, out, N);
}

// Round 11
// 397.354 us; speedup vs baseline: 3.1472x; 1.0634x over previous
//
#include <hip/hip_runtime.h>
#include <hip/hip_fp16.h>

#define BN_EPS 1e-5f
#define CAP 8192        // max edges per bucket (mean ~4092; 2x headroom)
#define MAXBKT 512      // supports N up to 131072 (src must fit 24 bits)

typedef _Float16 half8 __attribute__((ext_vector_type(8)));
typedef float f32x4 __attribute__((ext_vector_type(4)));

// ---------------- bucketed CSR build (packed: src | dstlo<<24) ----------------

__global__ void k_init(int* bucket_cur, int* rowptr, int n, int E) {
    int i = blockIdx.x * blockDim.x + threadIdx.x;
    if (i < MAXBKT) bucket_cur[i] = 0;
    if (i == 0) rowptr[n] = E;
}

__global__ __launch_bounds__(256) void k_bin(const int* __restrict__ src,
        const int* __restrict__ dst, int E, int nbk,
        int* __restrict__ bucket_cur, unsigned* __restrict__ pairs) {
    __shared__ int hist[MAXBKT];
    __shared__ int base_[MAXBKT];
    for (int b = threadIdx.x; b < nbk; b += 256) hist[b] = 0;
    __syncthreads();
    int e0 = blockIdx.x * 2048;
    int my_b[8], my_l[8];
    unsigned my_p[8];
    #pragma unroll
    for (int j = 0; j < 8; j++) {
        int e = e0 + threadIdx.x + j * 256;
        my_b[j] = -1;
        if (e < E) {
            int d = dst[e];
            my_p[j] = (unsigned)src[e] | ((unsigned)(d & 255) << 24);
            my_b[j] = d >> 8;
            my_l[j] = atomicAdd(&hist[my_b[j]], 1);
        }
    }
    __syncthreads();
    for (int b = threadIdx.x; b < nbk; b += 256) {
        int h = hist[b];
        base_[b] = h ? atomicAdd(&bucket_cur[b], h) : 0;
    }
    __syncthreads();
    #pragma unroll
    for (int j = 0; j < 8; j++) {
        if (my_b[j] >= 0) {
            int pos = base_[my_b[j]] + my_l[j];
            if (pos < CAP)
                pairs[(size_t)my_b[j] * CAP + pos] = my_p[j];
        }
    }
}

// exclusive scan of bucket totals -> bbase (single block; nbk <= 512)
__global__ void k_bsum(const int* __restrict__ bucket_cur, int* __restrict__ bbase, int nbk) {
    __shared__ int tmp[1024];
    int v = (threadIdx.x < nbk) ? min(bucket_cur[threadIdx.x], CAP) : 0;
    tmp[threadIdx.x] = v;
    __syncthreads();
    for (int off = 1; off < 1024; off <<= 1) {
        int t = (threadIdx.x >= off) ? tmp[threadIdx.x - off] : 0;
        __syncthreads();
        tmp[threadIdx.x] += t;
        __syncthreads();
    }
    if (threadIdx.x < nbk) bbase[threadIdx.x] = tmp[threadIdx.x] - v;  // exclusive
}

// per-bucket: hist + local scan + rowptr/dinv + scatter + contiguous stream-out
__global__ __launch_bounds__(256) void k_build(const unsigned* __restrict__ pairs,
        const int* __restrict__ bucket_cur, const int* __restrict__ bbase,
        int* __restrict__ rowptr, float* __restrict__ dinv,
        int* __restrict__ csr, int n) {
    __shared__ int lc[256];
    __shared__ int tmp[256];
    __shared__ int cur[256];
    __shared__ int stg[CAP];
    int b = blockIdx.x;
    int m = min(bucket_cur[b], CAP);
    const unsigned* p = pairs + (size_t)b * CAP;
    lc[threadIdx.x] = 0;
    __syncthreads();
    for (int q = threadIdx.x; q < m; q += 256)
        atomicAdd(&lc[p[q] >> 24], 1);
    __syncthreads();
    int v = lc[threadIdx.x];
    tmp[threadIdx.x] = v;
    __syncthreads();
    for (int off = 1; off < 256; off <<= 1) {
        int t = (threadIdx.x >= off) ? tmp[threadIdx.x - off] : 0;
        __syncthreads();
        tmp[threadIdx.x] += t;
        __syncthreads();
    }
    int local_excl = tmp[threadIdx.x] - v;
    int base_b = bbase[b];
    int node = b * 256 + threadIdx.x;
    if (node < n) {
        rowptr[node] = base_b + local_excl;
        dinv[node] = rsqrtf((float)v + 1.0f);
    }
    cur[threadIdx.x] = local_excl;
    __syncthreads();
    for (int q = threadIdx.x; q < m; q += 256) {
        unsigned pr = p[q];
        int ofs = atomicAdd(&cur[pr >> 24], 1);
        stg[ofs] = (int)(pr & 0xFFFFFFu);
    }
    __syncthreads();
    for (int q = threadIdx.x; q < m; q += 256)
        csr[base_b + q] = stg[q];
}

// ---------------- W pack: fp32 [128][M] -> fp16 hi/lo lane fragments ----------------

template<int M>
__global__ void k_wpack(const float* __restrict__ W, half8* __restrict__ Wp) {
    int idx = blockIdx.x * 256 + threadIdx.x;
    constexpr int TOT = (M / 16) * 4 * 64;
    if (idx >= TOT) return;
    int l = idx & 63, tc = idx >> 6;
    int c = tc & 3, t = tc >> 2;
    int g = l >> 4, nn = l & 15;
    int k0 = 32 * c + 8 * g, col = 16 * t + nn;
    half8 hi, lo;
    #pragma unroll
    for (int j = 0; j < 8; j++) {
        float w = W[(size_t)(k0 + j) * M + col];
        _Float16 h = (_Float16)w;
        hi[j] = h;
        lo[j] = (_Float16)(w - (float)h);
    }
    Wp[idx] = hi;
    Wp[TOT + idx] = lo;
}

// ---------------- helpers ----------------

__device__ __forceinline__ void h8_acc(float* acc, uint4 v) {
    const __half2* p = (const __half2*)&v;
    #pragma unroll
    for (int j = 0; j < 4; j++) {
        float2 f = __half22float2(p[j]);
        acc[2 * j] += f.x;
        acc[2 * j + 1] += f.y;
    }
}

// ---------------- layer-1 GEMM: ht16 = half( (x @ W1) * dinv ) ----------------

__global__ __launch_bounds__(256) void k_gemm_mfma1(const float* __restrict__ Ain,
        const half8* __restrict__ Wp, const float* __restrict__ dinv,
        __half* __restrict__ out, int n) {
    constexpr int LDR = 136;
    __shared__ _Float16 As[64 * LDR];

    int row0 = blockIdx.x * 64;
    for (int idx = threadIdx.x; idx < 64 * 16; idx += 256) {
        int r = idx >> 4, k2 = idx & 15;
        int grow = row0 + r;
        half8 h = {};
        if (grow < n) {
            float4 va = *(const float4*)&Ain[(size_t)grow * 128 + k2 * 8];
            float4 vb = *(const float4*)&Ain[(size_t)grow * 128 + k2 * 8 + 4];
            h[0] = (_Float16)va.x; h[1] = (_Float16)va.y;
            h[2] = (_Float16)va.z; h[3] = (_Float16)va.w;
            h[4] = (_Float16)vb.x; h[5] = (_Float16)vb.y;
            h[6] = (_Float16)vb.z; h[7] = (_Float16)vb.w;
        }
        *(half8*)&As[r * LDR + k2 * 8] = h;
    }
    __syncthreads();

    int w = threadIdx.x >> 6, l = threadIdx.x & 63;
    int g = l >> 4, nn = l & 15;

    half8 xf[4][4];
    #pragma unroll
    for (int rg = 0; rg < 4; rg++)
        #pragma unroll
        for (int c = 0; c < 4; c++)
            xf[rg][c] = *(const half8*)&As[(16 * rg + nn) * LDR + (4 * c + g) * 8];

    f32x4 acc[4][2];
    #pragma unroll
    for (int rg = 0; rg < 4; rg++)
        #pragma unroll
        for (int tt = 0; tt < 2; tt++)
            acc[rg][tt] = (f32x4){0.f, 0.f, 0.f, 0.f};

    #pragma unroll
    for (int tt = 0; tt < 2; tt++) {
        int t = w * 2 + tt;
        #pragma unroll
        for (int c = 0; c < 4; c++) {
            half8 wh = Wp[(t * 4 + c) * 64 + l];
            half8 wl = Wp[8 * 4 * 64 + (t * 4 + c) * 64 + l];
            #pragma unroll
            for (int rg = 0; rg < 4; rg++) {
                acc[rg][tt] = __builtin_amdgcn_mfma_f32_16x16x32_f16(wh, xf[rg][c], acc[rg][tt], 0, 0, 0);
                acc[rg][tt] = __builtin_amdgcn_mfma_f32_16x16x32_f16(wl, xf[rg][c], acc[rg][tt], 0, 0, 0);
            }
        }
    }

    __syncthreads();
    #pragma unroll
    for (int rg = 0; rg < 4; rg++) {
        int node = row0 + 16 * rg + nn;
        float s = (node < n) ? dinv[node] : 0.f;
        #pragma unroll
        for (int tt = 0; tt < 2; tt++) {
            int colh = 16 * (w * 2 + tt) + 4 * g;
            __half2 p0 = __float22half2_rn(make_float2(acc[rg][tt][0] * s, acc[rg][tt][1] * s));
            __half2 p1 = __float22half2_rn(make_float2(acc[rg][tt][2] * s, acc[rg][tt][3] * s));
            uint2 u;
            u.x = *(unsigned*)&p0;
            u.y = *(unsigned*)&p1;
            *(uint2*)&As[(16 * rg + nn) * LDR + colh] = u;
        }
    }
    __syncthreads();
    for (int idx = threadIdx.x; idx < 64 * 16; idx += 256) {
        int r = idx >> 4, k2 = idx & 15;
        int grow = row0 + r;
        if (grow < n)
            *(uint4*)&out[(size_t)grow * 128 + k2 * 8] = *(const uint4*)&As[r * LDR + k2 * 8];
    }
}

// ---------------- fused: agg_l (+bias+BN+ReLU) -> LDS -> GEMM_{l+1} ----------------
// unroll-4 (VGPR/occupancy sweet spot, R10 lesson); csr via nontemporal loads
// (read-once stream must not evict hot ht lines from L2).

template<int MOUT>
__global__ __launch_bounds__(256) void k_fused_mfma(const __half* __restrict__ ht,
        const int* __restrict__ rowptr, const int* __restrict__ csr,
        const float* __restrict__ dinv, const float* __restrict__ bias,
        const float* __restrict__ gw, const float* __restrict__ bb,
        const float* __restrict__ rm, const float* __restrict__ rv,
        const half8* __restrict__ Wp, __half* __restrict__ out, int n) {
    constexpr int NT = MOUT / 16;
    constexpr int TPW = NT / 4;
    constexpr int LDR = 136;
    __shared__ _Float16 As[64 * LDR];

    int row0 = blockIdx.x * 64;
    int grp = threadIdx.x >> 4;      // 0..15: node within pass
    int c = threadIdx.x & 15;        // uint4 index within 128-col row
    const uint4* h4 = (const uint4*)ht;
    int c0 = c * 8;
    float4 bv0 = *(const float4*)&bias[c0], bv1 = *(const float4*)&bias[c0 + 4];
    float gv[8], bbv[8], rmv[8], rvv[8];
    *(float4*)&gv[0] = *(const float4*)&gw[c0];  *(float4*)&gv[4] = *(const float4*)&gw[c0 + 4];
    *(float4*)&bbv[0] = *(const float4*)&bb[c0]; *(float4*)&bbv[4] = *(const float4*)&bb[c0 + 4];
    *(float4*)&rmv[0] = *(const float4*)&rm[c0]; *(float4*)&rmv[4] = *(const float4*)&rm[c0 + 4];
    *(float4*)&rvv[0] = *(const float4*)&rv[c0]; *(float4*)&rvv[4] = *(const float4*)&rv[c0 + 4];

    // ---- Phase A: aggregate + BN + ReLU for 64 nodes (4 passes of 16) ----
    for (int p = 0; p < 4; p++) {
        int r = p * 16 + grp;
        int i = row0 + r;
        uint4 u = make_uint4(0, 0, 0, 0);
        if (i < n) {
            float acc[8] = {};
            h8_acc(acc, h4[(size_t)i * 16 + c]);   // self loop
            int e1 = rowptr[i + 1];
            int e = rowptr[i];
            for (; e + 4 <= e1; e += 4) {
                int s0 = __builtin_nontemporal_load(csr + e);
                int s1 = __builtin_nontemporal_load(csr + e + 1);
                int s2 = __builtin_nontemporal_load(csr + e + 2);
                int s3 = __builtin_nontemporal_load(csr + e + 3);
                uint4 v0 = h4[(size_t)s0 * 16 + c];
                uint4 v1 = h4[(size_t)s1 * 16 + c];
                uint4 v2 = h4[(size_t)s2 * 16 + c];
                uint4 v3 = h4[(size_t)s3 * 16 + c];
                h8_acc(acc, v0); h8_acc(acc, v1); h8_acc(acc, v2); h8_acc(acc, v3);
            }
            for (; e < e1; e++)
                h8_acc(acc, h4[(size_t)__builtin_nontemporal_load(csr + e) * 16 + c]);
            float di = dinv[i];
            float o[8];
            o[0] = fmaf(acc[0], di, bv0.x); o[1] = fmaf(acc[1], di, bv0.y);
            o[2] = fmaf(acc[2], di, bv0.z); o[3] = fmaf(acc[3], di, bv0.w);
            o[4] = fmaf(acc[4], di, bv1.x); o[5] = fmaf(acc[5], di, bv1.y);
            o[6] = fmaf(acc[6], di, bv1.z); o[7] = fmaf(acc[7], di, bv1.w);
            #pragma unroll
            for (int j = 0; j < 8; j++)
                o[j] = fmaxf(fmaf(o[j] - rmv[j], rsqrtf(rvv[j] + BN_EPS) * gv[j], bbv[j]), 0.f);
            __half2 q0 = __float22half2_rn(make_float2(o[0], o[1]));
            __half2 q1 = __float22half2_rn(make_float2(o[2], o[3]));
            __half2 q2 = __float22half2_rn(make_float2(o[4], o[5]));
            __half2 q3 = __float22half2_rn(make_float2(o[6], o[7]));
            u.x = *(unsigned*)&q0; u.y = *(unsigned*)&q1;
            u.z = *(unsigned*)&q2; u.w = *(unsigned*)&q3;
        }
        *(uint4*)&As[r * LDR + c0] = u;
    }
    __syncthreads();

    // ---- Phase B: MFMA GEMM from LDS ----
    int w = threadIdx.x >> 6, l = threadIdx.x & 63;
    int g = l >> 4, nn = l & 15;

    half8 xf[4][4];
    #pragma unroll
    for (int rg = 0; rg < 4; rg++)
        #pragma unroll
        for (int cc = 0; cc < 4; cc++)
            xf[rg][cc] = *(const half8*)&As[(16 * rg + nn) * LDR + (4 * cc + g) * 8];

    f32x4 acc2[4][TPW];
    #pragma unroll
    for (int rg = 0; rg < 4; rg++)
        #pragma unroll
        for (int tt = 0; tt < TPW; tt++)
            acc2[rg][tt] = (f32x4){0.f, 0.f, 0.f, 0.f};

    #pragma unroll
    for (int tt = 0; tt < TPW; tt++) {
        int t = w * TPW + tt;
        #pragma unroll
        for (int cc = 0; cc < 4; cc++) {
            half8 wh = Wp[(t * 4 + cc) * 64 + l];
            half8 wl = Wp[NT * 4 * 64 + (t * 4 + cc) * 64 + l];
            #pragma unroll
            for (int rg = 0; rg < 4; rg++) {
                acc2[rg][tt] = __builtin_amdgcn_mfma_f32_16x16x32_f16(wh, xf[rg][cc], acc2[rg][tt], 0, 0, 0);
                acc2[rg][tt] = __builtin_amdgcn_mfma_f32_16x16x32_f16(wl, xf[rg][cc], acc2[rg][tt], 0, 0, 0);
            }
        }
    }

    __syncthreads();
    #pragma unroll
    for (int rg = 0; rg < 4; rg++) {
        int node = row0 + 16 * rg + nn;
        float s = (node < n) ? dinv[node] : 0.f;
        #pragma unroll
        for (int tt = 0; tt < TPW; tt++) {
            int colh = 16 * (w * TPW + tt) + 4 * g;
            __half2 p0 = __float22half2_rn(make_float2(acc2[rg][tt][0] * s, acc2[rg][tt][1] * s));
            __half2 p1 = __float22half2_rn(make_float2(acc2[rg][tt][2] * s, acc2[rg][tt][3] * s));
            uint2 uu;
            uu.x = *(unsigned*)&p0;
            uu.y = *(unsigned*)&p1;
            *(uint2*)&As[(16 * rg + nn) * LDR + colh] = uu;
        }
    }
    __syncthreads();
    for (int idx = threadIdx.x; idx < 64 * (MOUT / 8); idx += 256) {
        int r = idx / (MOUT / 8), k2 = idx % (MOUT / 8);
        int grow = row0 + r;
        if (grow < n)
            *(uint4*)&out[(size_t)grow * MOUT + k2 * 8] = *(const uint4*)&As[r * LDR + k2 * 8];
    }
}

// ---------------- fused: agg4 (64-col, +BN+ReLU) -> GEMM5 [64,2] -> htS fp32 ----------------

__global__ __launch_bounds__(256) void k_fused5(const __half* __restrict__ ht,
        const int* __restrict__ rowptr, const int* __restrict__ csr,
        const float* __restrict__ dinv, const float* __restrict__ bias,
        const float* __restrict__ gw, const float* __restrict__ bb,
        const float* __restrict__ rm, const float* __restrict__ rv,
        const float* __restrict__ W5, float* __restrict__ outS, int n) {
    constexpr int LDR = 72;
    __shared__ _Float16 As[64 * LDR];
    __shared__ float Wl[128];
    if (threadIdx.x < 128) Wl[threadIdx.x] = W5[threadIdx.x];

    int row0 = blockIdx.x * 64;
    int grp = threadIdx.x >> 3;      // 0..31: node within pass
    int c = threadIdx.x & 7;         // uint4 index within 64-col row
    const uint4* h4 = (const uint4*)ht;
    int c0 = c * 8;
    float4 bv0 = *(const float4*)&bias[c0], bv1 = *(const float4*)&bias[c0 + 4];
    float gv[8], bbv[8], rmv[8], rvv[8];
    *(float4*)&gv[0] = *(const float4*)&gw[c0];  *(float4*)&gv[4] = *(const float4*)&gw[c0 + 4];
    *(float4*)&bbv[0] = *(const float4*)&bb[c0]; *(float4*)&bbv[4] = *(const float4*)&bb[c0 + 4];
    *(float4*)&rmv[0] = *(const float4*)&rm[c0]; *(float4*)&rmv[4] = *(const float4*)&rm[c0 + 4];
    *(float4*)&rvv[0] = *(const float4*)&rv[c0]; *(float4*)&rvv[4] = *(const float4*)&rv[c0 + 4];

    for (int p = 0; p < 2; p++) {
        int r = p * 32 + grp;
        int i = row0 + r;
        uint4 u = make_uint4(0, 0, 0, 0);
        if (i < n) {
            float acc[8] = {};
            h8_acc(acc, h4[(size_t)i * 8 + c]);
            int e1 = rowptr[i + 1];
            int e = rowptr[i];
            for (; e + 4 <= e1; e += 4) {
                int s0 = __builtin_nontemporal_load(csr + e);
                int s1 = __builtin_nontemporal_load(csr + e + 1);
                int s2 = __builtin_nontemporal_load(csr + e + 2);
                int s3 = __builtin_nontemporal_load(csr + e + 3);
                uint4 v0 = h4[(size_t)s0 * 8 + c];
                uint4 v1 = h4[(size_t)s1 * 8 + c];
                uint4 v2 = h4[(size_t)s2 * 8 + c];
                uint4 v3 = h4[(size_t)s3 * 8 + c];
                h8_acc(acc, v0); h8_acc(acc, v1); h8_acc(acc, v2); h8_acc(acc, v3);
            }
            for (; e < e1; e++)
                h8_acc(acc, h4[(size_t)__builtin_nontemporal_load(csr + e) * 8 + c]);
            float di = dinv[i];
            float o[8];
            o[0] = fmaf(acc[0], di, bv0.x); o[1] = fmaf(acc[1], di, bv0.y);
            o[2] = fmaf(acc[2], di, bv0.z); o[3] = fmaf(acc[3], di, bv0.w);
            o[4] = fmaf(acc[4], di, bv1.x); o[5] = fmaf(acc[5], di, bv1.y);
            o[6] = fmaf(acc[6], di, bv1.z); o[7] = fmaf(acc[7], di, bv1.w);
            #pragma unroll
            for (int j = 0; j < 8; j++)
                o[j] = fmaxf(fmaf(o[j] - rmv[j], rsqrtf(rvv[j] + BN_EPS) * gv[j], bbv[j]), 0.f);
            __half2 q0 = __float22half2_rn(make_float2(o[0], o[1]));
            __half2 q1 = __float22half2_rn(make_float2(o[2], o[3]));
            __half2 q2 = __float22half2_rn(make_float2(o[4], o[5]));
            __half2 q3 = __float22half2_rn(make_float2(o[6], o[7]));
            u.x = *(unsigned*)&q0; u.y = *(unsigned*)&q1;
            u.z = *(unsigned*)&q2; u.w = *(unsigned*)&q3;
        }
        *(uint4*)&As[r * LDR + c0] = u;
    }
    __syncthreads();

    if (threadIdx.x < 128) {
        int r = threadIdx.x >> 1, cls = threadIdx.x & 1;
        int i = row0 + r;
        if (i < n) {
            float a = 0.f;
            const __half2* row = (const __half2*)&As[r * LDR];
            #pragma unroll
            for (int k2 = 0; k2 < 32; k2++) {
                float2 xx = __half22float2(row[k2]);
                a = fmaf(xx.x, Wl[4 * k2 + cls], a);
                a = fmaf(xx.y, Wl[4 * k2 + 2 + cls], a);
            }
            outS[2 * i + cls] = a * dinv[i];
        }
    }
}

// ---------------- final aggregation over htS fp32 (800KB, cache-resident) ----------------

__global__ void k_agg_final(const float* __restrict__ ht, const int* __restrict__ rowptr,
                            const int* __restrict__ csr, const float* __restrict__ dinv,
                            const float* __restrict__ bias, float* __restrict__ out, int n) {
    int i = blockIdx.x * blockDim.x + threadIdx.x;
    if (i >= n) return;
    const float2* h2 = (const float2*)ht;
    float2 t = h2[i];
    float a0 = t.x, a1 = t.y;
    int e1 = rowptr[i + 1];
    int e = rowptr[i];
    for (; e + 4 <= e1; e += 4) {
        int s0 = __builtin_nontemporal_load(csr + e);
        int s1 = __builtin_nontemporal_load(csr + e + 1);
        int s2 = __builtin_nontemporal_load(csr + e + 2);
        int s3 = __builtin_nontemporal_load(csr + e + 3);
        float2 u0 = h2[s0], u1 = h2[s1], u2 = h2[s2], u3 = h2[s3];
        a0 += (u0.x + u1.x) + (u2.x + u3.x);
        a1 += (u0.y + u1.y) + (u2.y + u3.y);
    }
    for (; e < e1; e++) {
        float2 u = h2[__builtin_nontemporal_load(csr + e)];
        a0 += u.x; a1 += u.y;
    }
    float s = dinv[i];
    out[2 * i]     = fmaf(a0, s, bias[0]);
    out[2 * i + 1] = fmaf(a1, s, bias[1]);
}

// ---------------- launch ----------------

extern "C" void kernel_launch(void* const* d_in, const int* in_sizes, int n_in,
                              void* d_out, int out_size, void* d_ws, size_t ws_size,
                              hipStream_t stream) {
    const float* x  = (const float*)d_in[0];
    const int*   ei = (const int*)d_in[1];
    const float* W1 = (const float*)d_in[2];  const float* b1 = (const float*)d_in[3];
    const float* W2 = (const float*)d_in[4];  const float* b2 = (const float*)d_in[5];
    const float* W3 = (const float*)d_in[6];  const float* b3 = (const float*)d_in[7];
    const float* W4 = (const float*)d_in[8];  const float* b4 = (const float*)d_in[9];
    const float* W5 = (const float*)d_in[10]; const float* b5 = (const float*)d_in[11];
    const float* g1 = (const float*)d_in[12]; const float* be1 = (const float*)d_in[13];
    const float* rm1 = (const float*)d_in[14]; const float* rv1 = (const float*)d_in[15];
    const float* g2 = (const float*)d_in[16]; const float* be2 = (const float*)d_in[17];
    const float* rm2 = (const float*)d_in[18]; const float* rv2 = (const float*)d_in[19];
    const float* g3 = (const float*)d_in[20]; const float* be3 = (const float*)d_in[21];
    const float* rm3 = (const float*)d_in[22]; const float* rv3 = (const float*)d_in[23];
    const float* g4 = (const float*)d_in[24]; const float* be4 = (const float*)d_in[25];
    const float* rm4 = (const float*)d_in[26]; const float* rv4 = (const float*)d_in[27];

    const int N = in_sizes[0] / 128;
    const int E = in_sizes[1] / 2;
    const int* src = ei;
    const int* dst = ei + E;
    const int nbk = (N + 255) >> 8;

    char* base = (char*)d_ws;
    size_t off = 0;
    auto carve = [&](size_t bytes) -> void* {
        void* r = base + off;
        off = (off + bytes + 255) & ~(size_t)255;
        return r;
    };
    __half* htA = (__half*)carve((size_t)N * 128 * 2);
    __half* htB = (__half*)carve((size_t)N * 128 * 2);
    float*  htS = (float*)carve((size_t)N * 2 * 4);
    half8*  Wp1 = (half8*)carve(2 * 8 * 4 * 64 * 16);
    half8*  Wp2 = (half8*)carve(2 * 8 * 4 * 64 * 16);
    half8*  Wp3 = (half8*)carve(2 * 8 * 4 * 64 * 16);
    half8*  Wp4 = (half8*)carve(2 * 4 * 4 * 64 * 16);
    unsigned* pairs = (unsigned*)carve((size_t)MAXBKT * CAP * 4);
    int*   bucket_cur = (int*)carve((size_t)MAXBKT * 4);
    int*   bbase = (int*)carve((size_t)MAXBKT * 4);
    int*   rowptr= (int*)carve((size_t)(N + 1) * 4);
    int*   csr   = (int*)carve((size_t)E * 4);
    float* dinv  = (float*)carve((size_t)N * 4);
    (void)ws_size; (void)n_in; (void)out_size;

    float* out = (float*)d_out;

    // weight packs
    k_wpack<128><<<8, 256, 0, stream>>>(W1, Wp1);
    k_wpack<128><<<8, 256, 0, stream>>>(W2, Wp2);
    k_wpack<128><<<8, 256, 0, stream>>>(W3, Wp3);
    k_wpack<64><<<4, 256, 0, stream>>>(W4, Wp4);

    // bucketed CSR build + degree (merged)
    k_init <<<(N + 255) / 256, 256, 0, stream>>>(bucket_cur, rowptr, N, E);
    k_bin  <<<(E + 2047) / 2048, 256, 0, stream>>>(src, dst, E, nbk, bucket_cur, pairs);
    k_bsum <<<1, 1024, 0, stream>>>(bucket_cur, bbase, nbk);
    k_build<<<nbk, 256, 0, stream>>>(pairs, bucket_cur, bbase, rowptr, dinv, csr, N);

    const int gb = (N + 63) / 64;
    // layer 1 GEMM
    k_gemm_mfma1<<<gb, 256, 0, stream>>>(x, Wp1, dinv, htA, N);
    // fused agg1 + GEMM2
    k_fused_mfma<128><<<gb, 256, 0, stream>>>(htA, rowptr, csr, dinv, b1, g1, be1, rm1, rv1, Wp2, htB, N);
    // fused agg2 + GEMM3
    k_fused_mfma<128><<<gb, 256, 0, stream>>>(htB, rowptr, csr, dinv, b2, g2, be2, rm2, rv2, Wp3, htA, N);
    // fused agg3 + GEMM4 (128 -> 64)
    k_fused_mfma<64><<<gb, 256, 0, stream>>>(htA, rowptr, csr, dinv, b3, g3, be3, rm3, rv3, Wp4, htB, N);
    // fused agg4 + GEMM5 (64 -> 2)
    k_fused5<<<gb, 256, 0, stream>>>(htB, rowptr, csr, dinv, b4, g4, be4, rm4, rv4, W5, htS, N);
    // final aggregation
    k_agg_final<<<(N + 255) / 256, 256, 0, stream>>>(htS, rowptr, csr, dinv, b5, out, N);
}

// Round 12
// 356.395 us; speedup vs baseline: 3.5089x; 1.1149x over previous
//
#include <hip/hip_runtime.h>
#include <hip/hip_fp16.h>

#define BN_EPS 1e-5f
#define CAP 8192        // max edges per bucket (mean ~4092; 2x headroom)
#define MAXBKT 512      // supports N up to 131072 (src must fit 24 bits)

typedef _Float16 half8 __attribute__((ext_vector_type(8)));
typedef float f32x4 __attribute__((ext_vector_type(4)));

// ---------------- bucketed CSR build (packed: src | dstlo<<24) ----------------

__global__ void k_init(int* bucket_cur, int* rowptr, int n, int E) {
    int i = blockIdx.x * blockDim.x + threadIdx.x;
    if (i < MAXBKT) bucket_cur[i] = 0;
    if (i == 0) rowptr[n] = E;
}

__global__ __launch_bounds__(256) void k_bin(const int* __restrict__ src,
        const int* __restrict__ dst, int E, int nbk,
        int* __restrict__ bucket_cur, unsigned* __restrict__ pairs) {
    __shared__ int hist[MAXBKT];
    __shared__ int base_[MAXBKT];
    for (int b = threadIdx.x; b < nbk; b += 256) hist[b] = 0;
    __syncthreads();
    int e0 = blockIdx.x * 2048;
    int my_b[8], my_l[8];
    unsigned my_p[8];
    #pragma unroll
    for (int j = 0; j < 8; j++) {
        int e = e0 + threadIdx.x + j * 256;
        my_b[j] = -1;
        if (e < E) {
            int d = dst[e];
            my_p[j] = (unsigned)src[e] | ((unsigned)(d & 255) << 24);
            my_b[j] = d >> 8;
            my_l[j] = atomicAdd(&hist[my_b[j]], 1);
        }
    }
    __syncthreads();
    for (int b = threadIdx.x; b < nbk; b += 256) {
        int h = hist[b];
        base_[b] = h ? atomicAdd(&bucket_cur[b], h) : 0;
    }
    __syncthreads();
    #pragma unroll
    for (int j = 0; j < 8; j++) {
        if (my_b[j] >= 0) {
            int pos = base_[my_b[j]] + my_l[j];
            if (pos < CAP)
                pairs[(size_t)my_b[j] * CAP + pos] = my_p[j];
        }
    }
}

// exclusive scan of bucket totals -> bbase (single block; nbk <= 512)
__global__ void k_bsum(const int* __restrict__ bucket_cur, int* __restrict__ bbase, int nbk) {
    __shared__ int tmp[1024];
    int v = (threadIdx.x < nbk) ? min(bucket_cur[threadIdx.x], CAP) : 0;
    tmp[threadIdx.x] = v;
    __syncthreads();
    for (int off = 1; off < 1024; off <<= 1) {
        int t = (threadIdx.x >= off) ? tmp[threadIdx.x - off] : 0;
        __syncthreads();
        tmp[threadIdx.x] += t;
        __syncthreads();
    }
    if (threadIdx.x < nbk) bbase[threadIdx.x] = tmp[threadIdx.x] - v;  // exclusive
}

// per-bucket: hist + local scan + rowptr/dinv + scatter + contiguous stream-out
__global__ __launch_bounds__(256) void k_build(const unsigned* __restrict__ pairs,
        const int* __restrict__ bucket_cur, const int* __restrict__ bbase,
        int* __restrict__ rowptr, float* __restrict__ dinv,
        int* __restrict__ csr, int n) {
    __shared__ int lc[256];
    __shared__ int tmp[256];
    __shared__ int cur[256];
    __shared__ int stg[CAP];
    int b = blockIdx.x;
    int m = min(bucket_cur[b], CAP);
    const unsigned* p = pairs + (size_t)b * CAP;
    lc[threadIdx.x] = 0;
    __syncthreads();
    for (int q = threadIdx.x; q < m; q += 256)
        atomicAdd(&lc[p[q] >> 24], 1);
    __syncthreads();
    int v = lc[threadIdx.x];
    tmp[threadIdx.x] = v;
    __syncthreads();
    for (int off = 1; off < 256; off <<= 1) {
        int t = (threadIdx.x >= off) ? tmp[threadIdx.x - off] : 0;
        __syncthreads();
        tmp[threadIdx.x] += t;
        __syncthreads();
    }
    int local_excl = tmp[threadIdx.x] - v;
    int base_b = bbase[b];
    int node = b * 256 + threadIdx.x;
    if (node < n) {
        rowptr[node] = base_b + local_excl;
        dinv[node] = rsqrtf((float)v + 1.0f);
    }
    cur[threadIdx.x] = local_excl;
    __syncthreads();
    for (int q = threadIdx.x; q < m; q += 256) {
        unsigned pr = p[q];
        int ofs = atomicAdd(&cur[pr >> 24], 1);
        stg[ofs] = (int)(pr & 0xFFFFFFu);
    }
    __syncthreads();
    for (int q = threadIdx.x; q < m; q += 256)
        csr[base_b + q] = stg[q];
}

// ---------------- W pack: fp32 [128][M] -> fp16 hi/lo lane fragments ----------------

template<int M>
__global__ void k_wpack(const float* __restrict__ W, half8* __restrict__ Wp) {
    int idx = blockIdx.x * 256 + threadIdx.x;
    constexpr int TOT = (M / 16) * 4 * 64;
    if (idx >= TOT) return;
    int l = idx & 63, tc = idx >> 6;
    int c = tc & 3, t = tc >> 2;
    int g = l >> 4, nn = l & 15;
    int k0 = 32 * c + 8 * g, col = 16 * t + nn;
    half8 hi, lo;
    #pragma unroll
    for (int j = 0; j < 8; j++) {
        float w = W[(size_t)(k0 + j) * M + col];
        _Float16 h = (_Float16)w;
        hi[j] = h;
        lo[j] = (_Float16)(w - (float)h);
    }
    Wp[idx] = hi;
    Wp[TOT + idx] = lo;
}

// ---------------- helpers ----------------

__device__ __forceinline__ void h8_acc(float* acc, uint4 v) {
    const __half2* p = (const __half2*)&v;
    #pragma unroll
    for (int j = 0; j < 4; j++) {
        float2 f = __half22float2(p[j]);
        acc[2 * j] += f.x;
        acc[2 * j + 1] += f.y;
    }
}

// ---------------- layer-1 GEMM: ht16 = half( (x @ W1) * dinv ) ----------------

__global__ __launch_bounds__(256) void k_gemm_mfma1(const float* __restrict__ Ain,
        const half8* __restrict__ Wp, const float* __restrict__ dinv,
        __half* __restrict__ out, int n) {
    constexpr int LDR = 136;
    __shared__ _Float16 As[64 * LDR];

    int row0 = blockIdx.x * 64;
    for (int idx = threadIdx.x; idx < 64 * 16; idx += 256) {
        int r = idx >> 4, k2 = idx & 15;
        int grow = row0 + r;
        half8 h = {};
        if (grow < n) {
            float4 va = *(const float4*)&Ain[(size_t)grow * 128 + k2 * 8];
            float4 vb = *(const float4*)&Ain[(size_t)grow * 128 + k2 * 8 + 4];
            h[0] = (_Float16)va.x; h[1] = (_Float16)va.y;
            h[2] = (_Float16)va.z; h[3] = (_Float16)va.w;
            h[4] = (_Float16)vb.x; h[5] = (_Float16)vb.y;
            h[6] = (_Float16)vb.z; h[7] = (_Float16)vb.w;
        }
        *(half8*)&As[r * LDR + k2 * 8] = h;
    }
    __syncthreads();

    int w = threadIdx.x >> 6, l = threadIdx.x & 63;
    int g = l >> 4, nn = l & 15;

    half8 xf[4][4];
    #pragma unroll
    for (int rg = 0; rg < 4; rg++)
        #pragma unroll
        for (int c = 0; c < 4; c++)
            xf[rg][c] = *(const half8*)&As[(16 * rg + nn) * LDR + (4 * c + g) * 8];

    f32x4 acc[4][2];
    #pragma unroll
    for (int rg = 0; rg < 4; rg++)
        #pragma unroll
        for (int tt = 0; tt < 2; tt++)
            acc[rg][tt] = (f32x4){0.f, 0.f, 0.f, 0.f};

    #pragma unroll
    for (int tt = 0; tt < 2; tt++) {
        int t = w * 2 + tt;
        #pragma unroll
        for (int c = 0; c < 4; c++) {
            half8 wh = Wp[(t * 4 + c) * 64 + l];
            half8 wl = Wp[8 * 4 * 64 + (t * 4 + c) * 64 + l];
            #pragma unroll
            for (int rg = 0; rg < 4; rg++) {
                acc[rg][tt] = __builtin_amdgcn_mfma_f32_16x16x32_f16(wh, xf[rg][c], acc[rg][tt], 0, 0, 0);
                acc[rg][tt] = __builtin_amdgcn_mfma_f32_16x16x32_f16(wl, xf[rg][c], acc[rg][tt], 0, 0, 0);
            }
        }
    }

    __syncthreads();
    #pragma unroll
    for (int rg = 0; rg < 4; rg++) {
        int node = row0 + 16 * rg + nn;
        float s = (node < n) ? dinv[node] : 0.f;
        #pragma unroll
        for (int tt = 0; tt < 2; tt++) {
            int colh = 16 * (w * 2 + tt) + 4 * g;
            __half2 p0 = __float22half2_rn(make_float2(acc[rg][tt][0] * s, acc[rg][tt][1] * s));
            __half2 p1 = __float22half2_rn(make_float2(acc[rg][tt][2] * s, acc[rg][tt][3] * s));
            uint2 u;
            u.x = *(unsigned*)&p0;
            u.y = *(unsigned*)&p1;
            *(uint2*)&As[(16 * rg + nn) * LDR + colh] = u;
        }
    }
    __syncthreads();
    for (int idx = threadIdx.x; idx < 64 * 16; idx += 256) {
        int r = idx >> 4, k2 = idx & 15;
        int grow = row0 + r;
        if (grow < n)
            *(uint4*)&out[(size_t)grow * 128 + k2 * 8] = *(const uint4*)&As[r * LDR + k2 * 8];
    }
}

// ---------------- fused: agg_l (+bias+BN+ReLU) -> LDS -> GEMM_{l+1} ----------------
// unroll-4 (VGPR/occupancy sweet spot); plain csr loads (nt hurt: R11).

template<int MOUT>
__global__ __launch_bounds__(256) void k_fused_mfma(const __half* __restrict__ ht,
        const int* __restrict__ rowptr, const int* __restrict__ csr,
        const float* __restrict__ dinv, const float* __restrict__ bias,
        const float* __restrict__ gw, const float* __restrict__ bb,
        const float* __restrict__ rm, const float* __restrict__ rv,
        const half8* __restrict__ Wp, __half* __restrict__ out, int n) {
    constexpr int NT = MOUT / 16;
    constexpr int TPW = NT / 4;
    constexpr int LDR = 136;
    __shared__ _Float16 As[64 * LDR];

    int row0 = blockIdx.x * 64;
    int grp = threadIdx.x >> 4;      // 0..15: node within pass
    int c = threadIdx.x & 15;        // uint4 index within 128-col row
    const uint4* h4 = (const uint4*)ht;
    int c0 = c * 8;
    float4 bv0 = *(const float4*)&bias[c0], bv1 = *(const float4*)&bias[c0 + 4];
    float gv[8], bbv[8], rmv[8], rvv[8];
    *(float4*)&gv[0] = *(const float4*)&gw[c0];  *(float4*)&gv[4] = *(const float4*)&gw[c0 + 4];
    *(float4*)&bbv[0] = *(const float4*)&bb[c0]; *(float4*)&bbv[4] = *(const float4*)&bb[c0 + 4];
    *(float4*)&rmv[0] = *(const float4*)&rm[c0]; *(float4*)&rmv[4] = *(const float4*)&rm[c0 + 4];
    *(float4*)&rvv[0] = *(const float4*)&rv[c0]; *(float4*)&rvv[4] = *(const float4*)&rv[c0 + 4];

    // ---- Phase A: aggregate + BN + ReLU for 64 nodes (4 passes of 16) ----
    for (int p = 0; p < 4; p++) {
        int r = p * 16 + grp;
        int i = row0 + r;
        uint4 u = make_uint4(0, 0, 0, 0);
        if (i < n) {
            float acc[8] = {};
            h8_acc(acc, h4[(size_t)i * 16 + c]);   // self loop
            int e1 = rowptr[i + 1];
            int e = rowptr[i];
            for (; e + 4 <= e1; e += 4) {
                int s0 = csr[e], s1 = csr[e + 1], s2 = csr[e + 2], s3 = csr[e + 3];
                uint4 v0 = h4[(size_t)s0 * 16 + c];
                uint4 v1 = h4[(size_t)s1 * 16 + c];
                uint4 v2 = h4[(size_t)s2 * 16 + c];
                uint4 v3 = h4[(size_t)s3 * 16 + c];
                h8_acc(acc, v0); h8_acc(acc, v1); h8_acc(acc, v2); h8_acc(acc, v3);
            }
            for (; e < e1; e++)
                h8_acc(acc, h4[(size_t)csr[e] * 16 + c]);
            float di = dinv[i];
            float o[8];
            o[0] = fmaf(acc[0], di, bv0.x); o[1] = fmaf(acc[1], di, bv0.y);
            o[2] = fmaf(acc[2], di, bv0.z); o[3] = fmaf(acc[3], di, bv0.w);
            o[4] = fmaf(acc[4], di, bv1.x); o[5] = fmaf(acc[5], di, bv1.y);
            o[6] = fmaf(acc[6], di, bv1.z); o[7] = fmaf(acc[7], di, bv1.w);
            #pragma unroll
            for (int j = 0; j < 8; j++)
                o[j] = fmaxf(fmaf(o[j] - rmv[j], rsqrtf(rvv[j] + BN_EPS) * gv[j], bbv[j]), 0.f);
            __half2 q0 = __float22half2_rn(make_float2(o[0], o[1]));
            __half2 q1 = __float22half2_rn(make_float2(o[2], o[3]));
            __half2 q2 = __float22half2_rn(make_float2(o[4], o[5]));
            __half2 q3 = __float22half2_rn(make_float2(o[6], o[7]));
            u.x = *(unsigned*)&q0; u.y = *(unsigned*)&q1;
            u.z = *(unsigned*)&q2; u.w = *(unsigned*)&q3;
        }
        *(uint4*)&As[r * LDR + c0] = u;
    }
    __syncthreads();

    // ---- Phase B: MFMA GEMM from LDS ----
    int w = threadIdx.x >> 6, l = threadIdx.x & 63;
    int g = l >> 4, nn = l & 15;

    half8 xf[4][4];
    #pragma unroll
    for (int rg = 0; rg < 4; rg++)
        #pragma unroll
        for (int cc = 0; cc < 4; cc++)
            xf[rg][cc] = *(const half8*)&As[(16 * rg + nn) * LDR + (4 * cc + g) * 8];

    f32x4 acc2[4][TPW];
    #pragma unroll
    for (int rg = 0; rg < 4; rg++)
        #pragma unroll
        for (int tt = 0; tt < TPW; tt++)
            acc2[rg][tt] = (f32x4){0.f, 0.f, 0.f, 0.f};

    #pragma unroll
    for (int tt = 0; tt < TPW; tt++) {
        int t = w * TPW + tt;
        #pragma unroll
        for (int cc = 0; cc < 4; cc++) {
            half8 wh = Wp[(t * 4 + cc) * 64 + l];
            half8 wl = Wp[NT * 4 * 64 + (t * 4 + cc) * 64 + l];
            #pragma unroll
            for (int rg = 0; rg < 4; rg++) {
                acc2[rg][tt] = __builtin_amdgcn_mfma_f32_16x16x32_f16(wh, xf[rg][cc], acc2[rg][tt], 0, 0, 0);
                acc2[rg][tt] = __builtin_amdgcn_mfma_f32_16x16x32_f16(wl, xf[rg][cc], acc2[rg][tt], 0, 0, 0);
            }
        }
    }

    __syncthreads();
    #pragma unroll
    for (int rg = 0; rg < 4; rg++) {
        int node = row0 + 16 * rg + nn;
        float s = (node < n) ? dinv[node] : 0.f;
        #pragma unroll
        for (int tt = 0; tt < TPW; tt++) {
            int colh = 16 * (w * TPW + tt) + 4 * g;
            __half2 p0 = __float22half2_rn(make_float2(acc2[rg][tt][0] * s, acc2[rg][tt][1] * s));
            __half2 p1 = __float22half2_rn(make_float2(acc2[rg][tt][2] * s, acc2[rg][tt][3] * s));
            uint2 uu;
            uu.x = *(unsigned*)&p0;
            uu.y = *(unsigned*)&p1;
            *(uint2*)&As[(16 * rg + nn) * LDR + colh] = uu;
        }
    }
    __syncthreads();
    for (int idx = threadIdx.x; idx < 64 * (MOUT / 8); idx += 256) {
        int r = idx / (MOUT / 8), k2 = idx % (MOUT / 8);
        int grow = row0 + r;
        if (grow < n)
            *(uint4*)&out[(size_t)grow * MOUT + k2 * 8] = *(const uint4*)&As[r * LDR + k2 * 8];
    }
}

// ---------------- fused: agg4 (64-col, +BN+ReLU) -> GEMM5 [64,2] -> htS fp32 ----------------

__global__ __launch_bounds__(256) void k_fused5(const __half* __restrict__ ht,
        const int* __restrict__ rowptr, const int* __restrict__ csr,
        const float* __restrict__ dinv, const float* __restrict__ bias,
        const float* __restrict__ gw, const float* __restrict__ bb,
        const float* __restrict__ rm, const float* __restrict__ rv,
        const float* __restrict__ W5, float* __restrict__ outS, int n) {
    constexpr int LDR = 72;
    __shared__ _Float16 As[64 * LDR];
    __shared__ float Wl[128];
    if (threadIdx.x < 128) Wl[threadIdx.x] = W5[threadIdx.x];

    int row0 = blockIdx.x * 64;
    int grp = threadIdx.x >> 3;      // 0..31: node within pass
    int c = threadIdx.x & 7;         // uint4 index within 64-col row
    const uint4* h4 = (const uint4*)ht;
    int c0 = c * 8;
    float4 bv0 = *(const float4*)&bias[c0], bv1 = *(const float4*)&bias[c0 + 4];
    float gv[8], bbv[8], rmv[8], rvv[8];
    *(float4*)&gv[0] = *(const float4*)&gw[c0];  *(float4*)&gv[4] = *(const float4*)&gw[c0 + 4];
    *(float4*)&bbv[0] = *(const float4*)&bb[c0]; *(float4*)&bbv[4] = *(const float4*)&bb[c0 + 4];
    *(float4*)&rmv[0] = *(const float4*)&rm[c0]; *(float4*)&rmv[4] = *(const float4*)&rm[c0 + 4];
    *(float4*)&rvv[0] = *(const float4*)&rv[c0]; *(float4*)&rvv[4] = *(const float4*)&rv[c0 + 4];

    for (int p = 0; p < 2; p++) {
        int r = p * 32 + grp;
        int i = row0 + r;
        uint4 u = make_uint4(0, 0, 0, 0);
        if (i < n) {
            float acc[8] = {};
            h8_acc(acc, h4[(size_t)i * 8 + c]);
            int e1 = rowptr[i + 1];
            int e = rowptr[i];
            for (; e + 4 <= e1; e += 4) {
                int s0 = csr[e], s1 = csr[e + 1], s2 = csr[e + 2], s3 = csr[e + 3];
                uint4 v0 = h4[(size_t)s0 * 8 + c];
                uint4 v1 = h4[(size_t)s1 * 8 + c];
                uint4 v2 = h4[(size_t)s2 * 8 + c];
                uint4 v3 = h4[(size_t)s3 * 8 + c];
                h8_acc(acc, v0); h8_acc(acc, v1); h8_acc(acc, v2); h8_acc(acc, v3);
            }
            for (; e < e1; e++)
                h8_acc(acc, h4[(size_t)csr[e] * 8 + c]);
            float di = dinv[i];
            float o[8];
            o[0] = fmaf(acc[0], di, bv0.x); o[1] = fmaf(acc[1], di, bv0.y);
            o[2] = fmaf(acc[2], di, bv0.z); o[3] = fmaf(acc[3], di, bv0.w);
            o[4] = fmaf(acc[4], di, bv1.x); o[5] = fmaf(acc[5], di, bv1.y);
            o[6] = fmaf(acc[6], di, bv1.z); o[7] = fmaf(acc[7], di, bv1.w);
            #pragma unroll
            for (int j = 0; j < 8; j++)
                o[j] = fmaxf(fmaf(o[j] - rmv[j], rsqrtf(rvv[j] + BN_EPS) * gv[j], bbv[j]), 0.f);
            __half2 q0 = __float22half2_rn(make_float2(o[0], o[1]));
            __half2 q1 = __float22half2_rn(make_float2(o[2], o[3]));
            __half2 q2 = __float22half2_rn(make_float2(o[4], o[5]));
            __half2 q3 = __float22half2_rn(make_float2(o[6], o[7]));
            u.x = *(unsigned*)&q0; u.y = *(unsigned*)&q1;
            u.z = *(unsigned*)&q2; u.w = *(unsigned*)&q3;
        }
        *(uint4*)&As[r * LDR + c0] = u;
    }
    __syncthreads();

    if (threadIdx.x < 128) {
        int r = threadIdx.x >> 1, cls = threadIdx.x & 1;
        int i = row0 + r;
        if (i < n) {
            float a = 0.f;
            const __half2* row = (const __half2*)&As[r * LDR];
            #pragma unroll
            for (int k2 = 0; k2 < 32; k2++) {
                float2 xx = __half22float2(row[k2]);
                a = fmaf(xx.x, Wl[4 * k2 + cls], a);
                a = fmaf(xx.y, Wl[4 * k2 + 2 + cls], a);
            }
            outS[2 * i + cls] = a * dinv[i];
        }
    }
}

// ---------------- final aggregation over htS fp32 (800KB, cache-resident) ----------------

__global__ void k_agg_final(const float* __restrict__ ht, const int* __restrict__ rowptr,
                            const int* __restrict__ csr, const float* __restrict__ dinv,
                            const float* __restrict__ bias, float* __restrict__ out, int n) {
    int i = blockIdx.x * blockDim.x + threadIdx.x;
    if (i >= n) return;
    const float2* h2 = (const float2*)ht;
    float2 t = h2[i];
    float a0 = t.x, a1 = t.y;
    int e1 = rowptr[i + 1];
    int e = rowptr[i];
    for (; e + 4 <= e1; e += 4) {
        int s0 = csr[e], s1 = csr[e + 1], s2 = csr[e + 2], s3 = csr[e + 3];
        float2 u0 = h2[s0], u1 = h2[s1], u2 = h2[s2], u3 = h2[s3];
        a0 += (u0.x + u1.x) + (u2.x + u3.x);
        a1 += (u0.y + u1.y) + (u2.y + u3.y);
    }
    for (; e < e1; e++) {
        float2 u = h2[csr[e]];
        a0 += u.x; a1 += u.y;
    }
    float s = dinv[i];
    out[2 * i]     = fmaf(a0, s, bias[0]);
    out[2 * i + 1] = fmaf(a1, s, bias[1]);
}

// ---------------- launch ----------------

extern "C" void kernel_launch(void* const* d_in, const int* in_sizes, int n_in,
                              void* d_out, int out_size, void* d_ws, size_t ws_size,
                              hipStream_t stream) {
    const float* x  = (const float*)d_in[0];
    const int*   ei = (const int*)d_in[1];
    const float* W1 = (const float*)d_in[2];  const float* b1 = (const float*)d_in[3];
    const float* W2 = (const float*)d_in[4];  const float* b2 = (const float*)d_in[5];
    const float* W3 = (const float*)d_in[6];  const float* b3 = (const float*)d_in[7];
    const float* W4 = (const float*)d_in[8];  const float* b4 = (const float*)d_in[9];
    const float* W5 = (const float*)d_in[10]; const float* b5 = (const float*)d_in[11];
    const float* g1 = (const float*)d_in[12]; const float* be1 = (const float*)d_in[13];
    const float* rm1 = (const float*)d_in[14]; const float* rv1 = (const float*)d_in[15];
    const float* g2 = (const float*)d_in[16]; const float* be2 = (const float*)d_in[17];
    const float* rm2 = (const float*)d_in[18]; const float* rv2 = (const float*)d_in[19];
    const float* g3 = (const float*)d_in[20]; const float* be3 = (const float*)d_in[21];
    const float* rm3 = (const float*)d_in[22]; const float* rv3 = (const float*)d_in[23];
    const float* g4 = (const float*)d_in[24]; const float* be4 = (const float*)d_in[25];
    const float* rm4 = (const float*)d_in[26]; const float* rv4 = (const float*)d_in[27];

    const int N = in_sizes[0] / 128;
    const int E = in_sizes[1] / 2;
    const int* src = ei;
    const int* dst = ei + E;
    const int nbk = (N + 255) >> 8;

    char* base = (char*)d_ws;
    size_t off = 0;
    auto carve = [&](size_t bytes) -> void* {
        void* r = base + off;
        off = (off + bytes + 255) & ~(size_t)255;
        return r;
    };
    __half* htA = (__half*)carve((size_t)N * 128 * 2);
    __half* htB = (__half*)carve((size_t)N * 128 * 2);
    float*  htS = (float*)carve((size_t)N * 2 * 4);
    half8*  Wp1 = (half8*)carve(2 * 8 * 4 * 64 * 16);
    half8*  Wp2 = (half8*)carve(2 * 8 * 4 * 64 * 16);
    half8*  Wp3 = (half8*)carve(2 * 8 * 4 * 64 * 16);
    half8*  Wp4 = (half8*)carve(2 * 4 * 4 * 64 * 16);
    unsigned* pairs = (unsigned*)carve((size_t)MAXBKT * CAP * 4);
    int*   bucket_cur = (int*)carve((size_t)MAXBKT * 4);
    int*   bbase = (int*)carve((size_t)MAXBKT * 4);
    int*   rowptr= (int*)carve((size_t)(N + 1) * 4);
    int*   csr   = (int*)carve((size_t)E * 4);
    float* dinv  = (float*)carve((size_t)N * 4);
    (void)ws_size; (void)n_in; (void)out_size;

    float* out = (float*)d_out;

    // weight packs
    k_wpack<128><<<8, 256, 0, stream>>>(W1, Wp1);
    k_wpack<128><<<8, 256, 0, stream>>>(W2, Wp2);
    k_wpack<128><<<8, 256, 0, stream>>>(W3, Wp3);
    k_wpack<64><<<4, 256, 0, stream>>>(W4, Wp4);

    // bucketed CSR build + degree (merged)
    k_init <<<(N + 255) / 256, 256, 0, stream>>>(bucket_cur, rowptr, N, E);
    k_bin  <<<(E + 2047) / 2048, 256, 0, stream>>>(src, dst, E, nbk, bucket_cur, pairs);
    k_bsum <<<1, 1024, 0, stream>>>(bucket_cur, bbase, nbk);
    k_build<<<nbk, 256, 0, stream>>>(pairs, bucket_cur, bbase, rowptr, dinv, csr, N);

    const int gb = (N + 63) / 64;
    // layer 1 GEMM
    k_gemm_mfma1<<<gb, 256, 0, stream>>>(x, Wp1, dinv, htA, N);
    // fused agg1 + GEMM2
    k_fused_mfma<128><<<gb, 256, 0, stream>>>(htA, rowptr, csr, dinv, b1, g1, be1, rm1, rv1, Wp2, htB, N);
    // fused agg2 + GEMM3
    k_fused_mfma<128><<<gb, 256, 0, stream>>>(htB, rowptr, csr, dinv, b2, g2, be2, rm2, rv2, Wp3, htA, N);
    // fused agg3 + GEMM4 (128 -> 64)
    k_fused_mfma<64><<<gb, 256, 0, stream>>>(htA, rowptr, csr, dinv, b3, g3, be3, rm3, rv3, Wp4, htB, N);
    // fused agg4 + GEMM5 (64 -> 2)
    k_fused5<<<gb, 256, 0, stream>>>(htB, rowptr, csr, dinv, b4, g4, be4, rm4, rv4, W5, htS, N);
    // final aggregation
    k_agg_final<<<(N + 255) / 256, 256, 0, stream>>>(htS, rowptr, csr, dinv, b5, out, N);
}